// Round 11
// baseline (289.009 us; speedup 1.0000x reference)
//
#include <hip/hip_runtime.h>
#include <hip/hip_fp16.h>
#include <cstdint>
#include <cstddef>

#define N_NODES 50000
#define N_EDGES 800000
#define DIM_IN 128
#define H_DIM 64
#define N_GRAPHS 256
#define EPS_BN 1e-5f
#define GEMM0_BLOCKS 782   // ceil(50000/64)
#define CBLK 128           // edge chunks for hist/fill
#define CHUNK 6250         // 800000 / 128
#define HWORDS4 6250       // 50000 nodes packed 8 x u4 per u32 (25KB)
#define SMEM_WORDS (DIM_IN * 64)   // 8192 u32 = 32KB (gemm Wl needs all of it)
#define FUSED_GRID 1024    // fill = bid%8==0 (XCD0-pinned), gemm0 = rest

struct __align__(16) h8 { __half2 a, b, c, d; };
struct __align__(8)  h4 { __half2 a, b; };

__device__ inline void fma4(float4& a, float s, const float4& w) {
    a.x = fmaf(s, w.x, a.x);
    a.y = fmaf(s, w.y, a.y);
    a.z = fmaf(s, w.z, a.z);
    a.w = fmaf(s, w.w, a.w);
}

__device__ inline h4 pack_h4(float4 v) {
    h4 r;
    r.a = __float22half2_rn(make_float2(v.x, v.y));
    r.b = __float22half2_rn(make_float2(v.z, v.w));
    return r;
}

// ---------- preprocessing (atomic-free CSR build) ----------

// per-chunk u4 LDS histogram -> histG[b*50000+n] (u8, contiguous per block)
// per-chunk per-node count is Binom(6250, 1/50000): P(>=16) ~ 1e-28 -> u4 safe.
__global__ __launch_bounds__(256) void count_hist_k(const int* __restrict__ dst,
                                                    unsigned char* __restrict__ histG) {
    __shared__ unsigned int h[HWORDS4];
    for (int i = threadIdx.x; i < HWORDS4; i += 256) h[i] = 0;
    __syncthreads();
    int base = blockIdx.x * CHUNK;
    for (int i = threadIdx.x; i < CHUNK; i += 256) {
        int n = dst[base + i];
        atomicAdd(&h[n >> 3], 1u << (4 * (n & 7)));
    }
    __syncthreads();
    unsigned char* out = histG + (size_t)blockIdx.x * N_NODES;
    for (int n = threadIdx.x; n < N_NODES; n += 256)
        out[n] = (h[n >> 3] >> (4 * (n & 7))) & 0xF;
}

// per-node scan across chunks: baseG[b][n] = sum_{b'<b} histG[b'][n]; counts[n]=deg
__global__ void blockscan_k(const unsigned char* __restrict__ histG,
                            unsigned char* __restrict__ baseG, int* __restrict__ counts) {
    int n = blockIdx.x * 256 + threadIdx.x;
    if (n >= N_NODES) return;
    int tot = 0;
    for (int b = 0; b < CBLK; b++) {
        unsigned char v = histG[(size_t)b * N_NODES + n];   // coalesced across threads
        baseG[(size_t)b * N_NODES + n] = (unsigned char)tot;
        tot += v;
    }
    counts[n] = tot;
}

__global__ void scan_block_k(const int* __restrict__ counts, int* __restrict__ offsets,
                             int* __restrict__ blocksums) {
    __shared__ int sh[1024];
    int i = blockIdx.x * 1024 + threadIdx.x;
    int v = (i < N_NODES) ? counts[i] : 0;
    sh[threadIdx.x] = v;
    __syncthreads();
    for (int off = 1; off < 1024; off <<= 1) {
        int t = (threadIdx.x >= off) ? sh[threadIdx.x - off] : 0;
        __syncthreads();
        sh[threadIdx.x] += t;
        __syncthreads();
    }
    if (i < N_NODES) offsets[i] = sh[threadIdx.x] - v;   // exclusive
    if (threadIdx.x == 1023) blocksums[blockIdx.x] = sh[1023];
}

__global__ void scan_sums_k(int* blocksums, int nb) {
    if (threadIdx.x == 0 && blockIdx.x == 0) {
        int run = 0;
        for (int b = 0; b < nb; b++) { int t = blocksums[b]; blocksums[b] = run; run += t; }
    }
}

__global__ void finalize_offsets_k(int* __restrict__ offsets,
                                   const int* __restrict__ counts,
                                   const int* __restrict__ blocksums,
                                   float* __restrict__ dinv) {
    int i = blockIdx.x * blockDim.x + threadIdx.x;
    if (i >= N_NODES) return;
    offsets[i] = offsets[i] + blocksums[i >> 10];
    dinv[i] = rsqrtf((float)(counts[i] + 1));   // +1 self loop
}

// ---------- fused: atomic-free CSR fill (XCD0-pinned) + gemm layer 0 ----------
// fill blocks are bid%8==0 -> all land on one XCD under round-robin dispatch, so
// the 1.6MB ssrc stays in ONE L2 and dirty lines assemble fully. gemm0 blocks
// use the remaining 7/8 of the grid. smem: fill uses 25KB (u4 hist), gemm 32KB (Wl).

__global__ __launch_bounds__(256) void gemm0_fill_k(
        const float* __restrict__ X, const float* __restrict__ W,
        const float* __restrict__ dinv, __half* __restrict__ hp,
        const int* __restrict__ src, const int* __restrict__ dst,
        const int* __restrict__ offsets, const unsigned char* __restrict__ baseG,
        unsigned short* __restrict__ ssrc) {
    __shared__ __align__(16) unsigned int smem[SMEM_WORDS];   // 8192 words = 32KB
    if ((blockIdx.x & 7) == 0) {
        int b = blockIdx.x >> 3;        // 0..127
        for (int i = threadIdx.x; i < HWORDS4; i += 256) smem[i] = 0;
        __syncthreads();
        int base = b * CHUNK;
        const unsigned char* myBase = baseG + (size_t)b * N_NODES;
        for (int i = threadIdx.x; i < CHUNK; i += 256) {
            int n = dst[base + i];
            int s = src[base + i];
            unsigned int old = atomicAdd(&smem[n >> 3], 1u << (4 * (n & 7)));
            int rank = (old >> (4 * (n & 7))) & 0xF;
            ssrc[offsets[n] + myBase[n] + rank] = (unsigned short)s;
        }
        return;
    }
    // ---- gemm0: gemm block index skips the fill slots ----
    int gb = blockIdx.x - (blockIdx.x >> 3) - 1;
    if (gb >= GEMM0_BLOCKS) return;
    float* Wl = (float*)smem;
    for (int i = threadIdx.x * 4; i < DIM_IN * 64; i += 256 * 4)
        *(float4*)&Wl[i] = *(const float4*)&W[i];
    __syncthreads();
    int c4 = (threadIdx.x & 15) * 4;
    int n0 = gb * 64 + (threadIdx.x >> 4) * 4;
    if (n0 >= N_NODES) return;
    const float* zr = X + (size_t)n0 * DIM_IN;
    float4 acc0 = {0,0,0,0}, acc1 = {0,0,0,0}, acc2 = {0,0,0,0}, acc3 = {0,0,0,0};
    #pragma unroll 4
    for (int k = 0; k < DIM_IN; k += 4) {
        float4 w0 = *(float4*)&Wl[(k + 0) * 64 + c4];
        float4 w1 = *(float4*)&Wl[(k + 1) * 64 + c4];
        float4 w2 = *(float4*)&Wl[(k + 2) * 64 + c4];
        float4 w3 = *(float4*)&Wl[(k + 3) * 64 + c4];
        float4 z0 = *(const float4*)&zr[0 * DIM_IN + k];
        float4 z1 = *(const float4*)&zr[1 * DIM_IN + k];
        float4 z2 = *(const float4*)&zr[2 * DIM_IN + k];
        float4 z3 = *(const float4*)&zr[3 * DIM_IN + k];
        fma4(acc0, z0.x, w0); fma4(acc0, z0.y, w1); fma4(acc0, z0.z, w2); fma4(acc0, z0.w, w3);
        fma4(acc1, z1.x, w0); fma4(acc1, z1.y, w1); fma4(acc1, z1.z, w2); fma4(acc1, z1.w, w3);
        fma4(acc2, z2.x, w0); fma4(acc2, z2.y, w1); fma4(acc2, z2.z, w2); fma4(acc2, z2.w, w3);
        fma4(acc3, z3.x, w0); fma4(acc3, z3.y, w1); fma4(acc3, z3.z, w2); fma4(acc3, z3.w, w3);
    }
    float d0 = dinv[n0], d1 = dinv[n0 + 1], d2 = dinv[n0 + 2], d3 = dinv[n0 + 3];
    acc0.x *= d0; acc0.y *= d0; acc0.z *= d0; acc0.w *= d0;
    acc1.x *= d1; acc1.y *= d1; acc1.z *= d1; acc1.w *= d1;
    acc2.x *= d2; acc2.y *= d2; acc2.z *= d2; acc2.w *= d2;
    acc3.x *= d3; acc3.y *= d3; acc3.z *= d3; acc3.w *= d3;
    *(h4*)&hp[(size_t)(n0 + 0) * 64 + c4] = pack_h4(acc0);
    *(h4*)&hp[(size_t)(n0 + 1) * 64 + c4] = pack_h4(acc1);
    *(h4*)&hp[(size_t)(n0 + 2) * 64 + c4] = pack_h4(acc2);
    *(h4*)&hp[(size_t)(n0 + 3) * 64 + c4] = pack_h4(acc3);
}

// ---------- gemm layers 1/2: fp16 zb input + BN affine, fp16*dinv out ----------

__global__ __launch_bounds__(256) void gemm_h_k(
        const __half* __restrict__ Z, const float* __restrict__ W,
        const float* __restrict__ scale, const float* __restrict__ shift,
        const float* __restrict__ dinv, __half* __restrict__ hp) {
    __shared__ float Wl[H_DIM * 64];
    __shared__ float scl[64], shl[64];
    for (int i = threadIdx.x * 4; i < H_DIM * 64; i += 256 * 4)
        *(float4*)&Wl[i] = *(const float4*)&W[i];
    if (threadIdx.x < 64) { scl[threadIdx.x] = scale[threadIdx.x]; shl[threadIdx.x] = shift[threadIdx.x]; }
    __syncthreads();
    int c4 = (threadIdx.x & 15) * 4;
    int n0 = blockIdx.x * 64 + (threadIdx.x >> 4) * 4;
    if (n0 >= N_NODES) return;
    float4 acc0 = {0,0,0,0}, acc1 = {0,0,0,0}, acc2 = {0,0,0,0}, acc3 = {0,0,0,0};
    #pragma unroll 4
    for (int k = 0; k < H_DIM; k += 4) {
        float4 w0 = *(float4*)&Wl[(k + 0) * 64 + c4];
        float4 w1 = *(float4*)&Wl[(k + 1) * 64 + c4];
        float4 w2 = *(float4*)&Wl[(k + 2) * 64 + c4];
        float4 w3 = *(float4*)&Wl[(k + 3) * 64 + c4];
        float4 s4 = *(float4*)&scl[k];
        float4 f4 = *(float4*)&shl[k];
        #define DO_NODE(ACC, I)                                                        \
        {   h4 r = *(const h4*)&Z[(size_t)(n0 + I) * 64 + k];                          \
            float2 p = __half22float2(r.a), q = __half22float2(r.b);                   \
            float z0 = fmaf(p.x, s4.x, f4.x), z1 = fmaf(p.y, s4.y, f4.y);              \
            float z2 = fmaf(q.x, s4.z, f4.z), z3 = fmaf(q.y, s4.w, f4.w);              \
            fma4(ACC, z0, w0); fma4(ACC, z1, w1); fma4(ACC, z2, w2); fma4(ACC, z3, w3); }
        DO_NODE(acc0, 0) DO_NODE(acc1, 1) DO_NODE(acc2, 2) DO_NODE(acc3, 3)
        #undef DO_NODE
    }
    float d0 = dinv[n0], d1 = dinv[n0 + 1], d2 = dinv[n0 + 2], d3 = dinv[n0 + 3];
    acc0.x *= d0; acc0.y *= d0; acc0.z *= d0; acc0.w *= d0;
    acc1.x *= d1; acc1.y *= d1; acc1.z *= d1; acc1.w *= d1;
    acc2.x *= d2; acc2.y *= d2; acc2.z *= d2; acc2.w *= d2;
    acc3.x *= d3; acc3.y *= d3; acc3.z *= d3; acc3.w *= d3;
    *(h4*)&hp[(size_t)(n0 + 0) * 64 + c4] = pack_h4(acc0);
    *(h4*)&hp[(size_t)(n0 + 1) * 64 + c4] = pack_h4(acc1);
    *(h4*)&hp[(size_t)(n0 + 2) * 64 + c4] = pack_h4(acc2);
    *(h4*)&hp[(size_t)(n0 + 3) * 64 + c4] = pack_h4(acc3);
}

// ---------- aggregate + relu (pure gather, x2 edge ILP) ----------

__global__ __launch_bounds__(256) void aggregate_k(
        const __half* __restrict__ hp, const float* __restrict__ dinv,
        const int* __restrict__ offsets, const int* __restrict__ counts,
        const unsigned short* __restrict__ ssrc, const float* __restrict__ bias,
        __half* __restrict__ zb) {
    int wid = (blockIdx.x * blockDim.x + threadIdx.x) >> 6;   // node (grid exact)
    int lane = threadIdx.x & 63;
    int g = lane >> 3;            // edge sub-slot 0..7
    int c8 = (lane & 7) * 8;      // channel base
    float a0=0,a1=0,a2=0,a3=0,a4=0,a5=0,a6=0,a7=0;
    int s0 = offsets[wid];
    int ce = counts[wid];
    int e = g;
    for (; e + 8 < ce; e += 16) {
        int s1 = ssrc[s0 + e];
        int s2 = ssrc[s0 + e + 8];
        h8 v1 = *(const h8*)(hp + (size_t)s1 * 64 + c8);
        h8 v2 = *(const h8*)(hp + (size_t)s2 * 64 + c8);
        float2 f0 = __half22float2(v1.a), f1 = __half22float2(v1.b);
        float2 f2 = __half22float2(v1.c), f3 = __half22float2(v1.d);
        float2 g0 = __half22float2(v2.a), g1 = __half22float2(v2.b);
        float2 g2 = __half22float2(v2.c), g3 = __half22float2(v2.d);
        a0 += f0.x + g0.x; a1 += f0.y + g0.y; a2 += f1.x + g1.x; a3 += f1.y + g1.y;
        a4 += f2.x + g2.x; a5 += f2.y + g2.y; a6 += f3.x + g3.x; a7 += f3.y + g3.y;
    }
    if (e < ce) {
        int s = ssrc[s0 + e];
        h8 v = *(const h8*)(hp + (size_t)s * 64 + c8);
        float2 f0 = __half22float2(v.a), f1 = __half22float2(v.b);
        float2 f2 = __half22float2(v.c), f3 = __half22float2(v.d);
        a0 += f0.x; a1 += f0.y; a2 += f1.x; a3 += f1.y;
        a4 += f2.x; a5 += f2.y; a6 += f3.x; a7 += f3.y;
    }
    #define RED(A) A += __shfl_xor(A, 8); A += __shfl_xor(A, 16); A += __shfl_xor(A, 32);
    RED(a0) RED(a1) RED(a2) RED(a3) RED(a4) RED(a5) RED(a6) RED(a7)
    #undef RED
    if (g == 0) {
        h8 sv = *(const h8*)(hp + (size_t)wid * 64 + c8);
        float2 f0 = __half22float2(sv.a), f1 = __half22float2(sv.b);
        float2 f2 = __half22float2(sv.c), f3 = __half22float2(sv.d);
        float di = dinv[wid];
        float4 b0 = *(const float4*)&bias[c8];
        float4 b1 = *(const float4*)&bias[c8 + 4];
        float o0 = fmaxf(fmaf(a0 + f0.x, di, b0.x), 0.f);
        float o1 = fmaxf(fmaf(a1 + f0.y, di, b0.y), 0.f);
        float o2 = fmaxf(fmaf(a2 + f1.x, di, b0.z), 0.f);
        float o3 = fmaxf(fmaf(a3 + f1.y, di, b0.w), 0.f);
        float o4 = fmaxf(fmaf(a4 + f2.x, di, b1.x), 0.f);
        float o5 = fmaxf(fmaf(a5 + f2.y, di, b1.y), 0.f);
        float o6 = fmaxf(fmaf(a6 + f3.x, di, b1.z), 0.f);
        float o7 = fmaxf(fmaf(a7 + f3.y, di, b1.w), 0.f);
        h8 ov;
        ov.a = __float22half2_rn(make_float2(o0, o1));
        ov.b = __float22half2_rn(make_float2(o2, o3));
        ov.c = __float22half2_rn(make_float2(o4, o5));
        ov.d = __float22half2_rn(make_float2(o6, o7));
        *(h8*)(zb + (size_t)wid * 64 + c8) = ov;
    }
}

// ---------- BN stats: streaming over zb, 8 replica slots ----------

__global__ __launch_bounds__(256) void bn_stats_k(const __half* __restrict__ zb,
                                                  float* __restrict__ slots) {
    int slot = threadIdx.x & 7;      // channel octet
    int rp = threadIdx.x >> 3;       // row phase 0..31
    float s[8], q[8];
    #pragma unroll
    for (int j = 0; j < 8; j++) { s[j] = 0.f; q[j] = 0.f; }
    for (int n = blockIdx.x * 32 + rp; n < N_NODES; n += 256 * 32) {
        h8 v = *(const h8*)(zb + (size_t)n * 64 + slot * 8);
        float2 f0 = __half22float2(v.a), f1 = __half22float2(v.b);
        float2 f2 = __half22float2(v.c), f3 = __half22float2(v.d);
        float x0 = f0.x, x1 = f0.y, x2 = f1.x, x3 = f1.y;
        float x4 = f2.x, x5 = f2.y, x6 = f3.x, x7 = f3.y;
        s[0] += x0; q[0] += x0 * x0; s[1] += x1; q[1] += x1 * x1;
        s[2] += x2; q[2] += x2 * x2; s[3] += x3; q[3] += x3 * x3;
        s[4] += x4; q[4] += x4 * x4; s[5] += x5; q[5] += x5 * x5;
        s[6] += x6; q[6] += x6 * x6; s[7] += x7; q[7] += x7 * x7;
    }
    #pragma unroll
    for (int j = 0; j < 8; j++) {
        float a = s[j];
        a += __shfl_xor(a, 8); a += __shfl_xor(a, 16); a += __shfl_xor(a, 32);
        s[j] = a;
        float b = q[j];
        b += __shfl_xor(b, 8); b += __shfl_xor(b, 16); b += __shfl_xor(b, 32);
        q[j] = b;
    }
    __shared__ float rs[4][64], rq[4][64];
    int w = threadIdx.x >> 6;
    if ((threadIdx.x & 63) < 8) {
        #pragma unroll
        for (int j = 0; j < 8; j++) {
            rs[w][slot * 8 + j] = s[j];
            rq[w][slot * 8 + j] = q[j];
        }
    }
    __syncthreads();
    int t = threadIdx.x;
    int rep = (blockIdx.x & 7) * 128;
    if (t < 64)
        atomicAdd(&slots[rep + t], rs[0][t] + rs[1][t] + rs[2][t] + rs[3][t]);
    else if (t < 128) {
        int c = t - 64;
        atomicAdd(&slots[rep + t], rq[0][c] + rq[1][c] + rq[2][c] + rq[3][c]);
    }
}

// reduce 8 replica slots -> scale/shift, then re-zero slots for next layer
__global__ void bn_finalize_k(float* __restrict__ slots,
                              const float* __restrict__ gamma, const float* __restrict__ beta,
                              float* __restrict__ scale, float* __restrict__ shift) {
    __shared__ float red[128];
    int c = threadIdx.x;   // 0..127
    float v = 0.f;
    #pragma unroll
    for (int r = 0; r < 8; r++) v += slots[r * 128 + c];
    red[c] = v;
    __syncthreads();
    if (c < 64) {
        float mu = red[c] * (1.0f / N_NODES);
        float var = red[c + 64] * (1.0f / N_NODES) - mu * mu;
        float k = gamma[c] * rsqrtf(var + EPS_BN);
        scale[c] = k;
        shift[c] = beta[c] - mu * k;
    }
    #pragma unroll
    for (int i = 0; i < 8; i++) slots[i * 128 + c] = 0.f;
}

// ---------- epilogue ----------

__global__ __launch_bounds__(256) void pool_k(
        const __half* __restrict__ zb0, const __half* __restrict__ zb1,
        const __half* __restrict__ zb2,
        const float* __restrict__ scaleAll, const float* __restrict__ shiftAll,
        const int* __restrict__ batch, float* __restrict__ gc) {
    int g = blockIdx.x;
    int lo = 0, hi = N_NODES;
    while (lo < hi) { int mid = (lo + hi) >> 1; if (batch[mid] < g) lo = mid + 1; else hi = mid; }
    int start = lo;
    hi = N_NODES;
    while (lo < hi) { int mid = (lo + hi) >> 1; if (batch[mid] < g + 1) lo = mid + 1; else hi = mid; }
    int end = lo;

    int slot = threadIdx.x & 7;
    int r = threadIdx.x >> 3;        // 0..31
    const __half* zbs[3] = {zb0, zb1, zb2};
    float acc[3][8];
    #pragma unroll
    for (int l = 0; l < 3; l++)
        #pragma unroll
        for (int j = 0; j < 8; j++) acc[l][j] = 0.f;
    #pragma unroll
    for (int l = 0; l < 3; l++) {
        const __half* z = zbs[l];
        for (int n = start + r; n < end; n += 32) {
            h8 v = *(const h8*)(z + (size_t)n * 64 + slot * 8);
            float2 f0 = __half22float2(v.a), f1 = __half22float2(v.b);
            float2 f2 = __half22float2(v.c), f3 = __half22float2(v.d);
            acc[l][0] += f0.x; acc[l][1] += f0.y; acc[l][2] += f1.x; acc[l][3] += f1.y;
            acc[l][4] += f2.x; acc[l][5] += f2.y; acc[l][6] += f3.x; acc[l][7] += f3.y;
        }
    }
    #pragma unroll
    for (int l = 0; l < 3; l++)
        #pragma unroll
        for (int j = 0; j < 8; j++) {
            float a = acc[l][j];
            a += __shfl_xor(a, 8);
            a += __shfl_xor(a, 16);
            a += __shfl_xor(a, 32);
            acc[l][j] = a;
        }
    __shared__ float red[4][3][64];
    int w = threadIdx.x >> 6;
    if ((threadIdx.x & 63) < 8) {
        #pragma unroll
        for (int l = 0; l < 3; l++)
            #pragma unroll
            for (int j = 0; j < 8; j++)
                red[w][l][slot * 8 + j] = acc[l][j];
    }
    __syncthreads();
    __shared__ float part[4];
    int t = threadIdx.x;
    float m = 0.f;
    if (t < 192) {
        int l = t >> 6, ch = t & 63;
        float s = red[0][l][ch] + red[1][l][ch] + red[2][l][ch] + red[3][l][ch];
        m = (end > start) ? fmaf(scaleAll[t], s / (float)(end - start), shiftAll[t]) : 0.f;
    }
    float q = m * m;
    #pragma unroll
    for (int off = 32; off; off >>= 1) q += __shfl_xor(q, off);
    if ((t & 63) == 0) part[t >> 6] = q;
    __syncthreads();
    float inv = 1.0f / fmaxf(sqrtf(part[0] + part[1] + part[2] + part[3]), 1e-12f);
    if (t < 192) gc[(size_t)g * 192 + t] = m * inv;
}

__global__ __launch_bounds__(256) void l2norm_zc_k(
        const __half* __restrict__ zb0, const __half* __restrict__ zb1,
        const __half* __restrict__ zb2,
        const float* __restrict__ scaleAll, const float* __restrict__ shiftAll,
        float* __restrict__ zc) {
    int wid = (blockIdx.x * blockDim.x + threadIdx.x) >> 6;
    int lane = threadIdx.x & 63;
    float a = fmaf(__half2float(zb0[(size_t)wid * 64 + lane]), scaleAll[lane],       shiftAll[lane]);
    float b = fmaf(__half2float(zb1[(size_t)wid * 64 + lane]), scaleAll[64 + lane],  shiftAll[64 + lane]);
    float c = fmaf(__half2float(zb2[(size_t)wid * 64 + lane]), scaleAll[128 + lane], shiftAll[128 + lane]);
    float s = a * a + b * b + c * c;
    #pragma unroll
    for (int off = 32; off; off >>= 1) s += __shfl_xor(s, off);
    float inv = 1.0f / fmaxf(sqrtf(s), 1e-12f);
    float* row = zc + (size_t)wid * 192;
    row[lane] = a * inv; row[lane + 64] = b * inv; row[lane + 128] = c * inv;
}

// ---------- launch ----------

extern "C" void kernel_launch(void* const* d_in, const int* in_sizes, int n_in,
                              void* d_out, int out_size, void* d_ws, size_t ws_size,
                              hipStream_t stream) {
    const float* x     = (const float*)d_in[0];
    const int*   ei    = (const int*)d_in[1];
    const int*   batch = (const int*)d_in[2];
    const float* W[3]     = {(const float*)d_in[3],  (const float*)d_in[7],  (const float*)d_in[11]};
    const float* bias[3]  = {(const float*)d_in[4],  (const float*)d_in[8],  (const float*)d_in[12]};
    const float* gamma[3] = {(const float*)d_in[5],  (const float*)d_in[9],  (const float*)d_in[13]};
    const float* beta[3]  = {(const float*)d_in[6],  (const float*)d_in[10], (const float*)d_in[14]};
    const int* src = ei;
    const int* dst = ei + N_EDGES;

    float* out = (float*)d_out;
    float* zc = out;                                // [N, 192]
    float* gc = out + (size_t)N_NODES * 192;        // [G, 192]

    char* w = (char*)d_ws;
    auto alloc = [&](size_t bytes) -> void* {
        void* p = (void*)w;
        w += (bytes + 255) / 256 * 256;
        return p;
    };
    int*            counts    = (int*)alloc(N_NODES * 4);
    int*            offsets   = (int*)alloc(N_NODES * 4);
    int*            blocksums = (int*)alloc(64 * 4);
    float*          dinv      = (float*)alloc(N_NODES * 4);
    unsigned short* ssrc      = (unsigned short*)alloc(N_EDGES * 2);
    __half*         hp        = (__half*)alloc((size_t)N_NODES * 64 * 2);
    __half*         zb[3];
    zb[0] = (__half*)alloc((size_t)N_NODES * 64 * 2);
    zb[1] = (__half*)alloc((size_t)N_NODES * 64 * 2);
    zb[2] = (__half*)alloc((size_t)N_NODES * 64 * 2);
    float*          slots     = (float*)alloc(8 * 128 * 4);
    float*          scaleAll  = (float*)alloc(192 * 4);
    float*          shiftAll  = (float*)alloc(192 * 4);
    // histG overlays zb[1], baseG overlays zb[2] (each CBLK*N_NODES u8 = 6.4MB).
    // Strictly sequential lifetimes; fully rewritten every call (replay-safe).
    unsigned char* histG = (unsigned char*)zb[1];
    unsigned char* baseG = (unsigned char*)zb[2];

    const int nscan = (N_NODES + 1023) / 1024;   // 49

    hipMemsetAsync(slots, 0, 8 * 128 * 4, stream);
    count_hist_k<<<CBLK, 256, 0, stream>>>(dst, histG);
    blockscan_k<<<(N_NODES + 255) / 256, 256, 0, stream>>>(histG, baseG, counts);
    scan_block_k<<<nscan, 1024, 0, stream>>>(counts, offsets, blocksums);
    scan_sums_k<<<1, 64, 0, stream>>>(blocksums, nscan);
    finalize_offsets_k<<<(N_NODES + 255) / 256, 256, 0, stream>>>(offsets, counts, blocksums, dinv);

    gemm0_fill_k<<<FUSED_GRID, 256, 0, stream>>>(x, W[0], dinv, hp,
                                                 src, dst, offsets, baseG, ssrc);

    const int aggBlocks = N_NODES / 4;   // 12500, exact

    for (int l = 0; l < 3; l++) {
        if (l > 0)
            gemm_h_k<<<GEMM0_BLOCKS, 256, 0, stream>>>(zb[l - 1], W[l],
                                                       scaleAll + (l - 1) * 64, shiftAll + (l - 1) * 64,
                                                       dinv, hp);
        aggregate_k<<<aggBlocks, 256, 0, stream>>>(hp, dinv, offsets, counts, ssrc,
                                                   bias[l], zb[l]);
        bn_stats_k<<<256, 256, 0, stream>>>(zb[l], slots);
        bn_finalize_k<<<1, 128, 0, stream>>>(slots, gamma[l], beta[l],
                                             scaleAll + l * 64, shiftAll + l * 64);
    }

    pool_k<<<N_GRAPHS, 256, 0, stream>>>(zb[0], zb[1], zb[2], scaleAll, shiftAll, batch, gc);
    l2norm_zc_k<<<N_NODES / 4, 256, 0, stream>>>(zb[0], zb[1], zb[2], scaleAll, shiftAll, zc);
}

// Round 12
// 225.719 us; speedup vs baseline: 1.2804x; 1.2804x over previous
//
#include <hip/hip_runtime.h>
#include <hip/hip_fp16.h>
#include <cstdint>
#include <cstddef>

#define N_NODES 50000
#define N_EDGES 800000
#define DIM_IN 128
#define H_DIM 64
#define N_GRAPHS 256
#define EPS_BN 1e-5f
#define GEMM0_BLOCKS 782   // ceil(50000/64)
#define CBLK 128           // edge chunks for hist/fill
#define CHUNK 6250         // 800000 / 128
#define HWORDS4 6250       // 50000 nodes packed 8 x u4 per u32 (25KB)
#define SMEM_WORDS (DIM_IN * 64)   // 8192 u32 = 32KB (gemm Wl needs all of it)

struct __align__(16) h8 { __half2 a, b, c, d; };
struct __align__(8)  h4 { __half2 a, b; };

__device__ inline void fma4(float4& a, float s, const float4& w) {
    a.x = fmaf(s, w.x, a.x);
    a.y = fmaf(s, w.y, a.y);
    a.z = fmaf(s, w.z, a.z);
    a.w = fmaf(s, w.w, a.w);
}

__device__ inline h4 pack_h4(float4 v) {
    h4 r;
    r.a = __float22half2_rn(make_float2(v.x, v.y));
    r.b = __float22half2_rn(make_float2(v.z, v.w));
    return r;
}

// ---------- preprocessing (atomic-free CSR build) ----------

// per-chunk u4 LDS histogram -> histG[b*50000+n] (u8, contiguous per block)
// per-chunk per-node count is Binom(6250, 1/50000): P(>=16) ~ 1e-28 -> u4 safe.
__global__ __launch_bounds__(256) void count_hist_k(const int* __restrict__ dst,
                                                    unsigned char* __restrict__ histG) {
    __shared__ unsigned int h[HWORDS4];
    for (int i = threadIdx.x; i < HWORDS4; i += 256) h[i] = 0;
    __syncthreads();
    int base = blockIdx.x * CHUNK;
    for (int i = threadIdx.x; i < CHUNK; i += 256) {
        int n = dst[base + i];
        atomicAdd(&h[n >> 3], 1u << (4 * (n & 7)));
    }
    __syncthreads();
    unsigned char* out = histG + (size_t)blockIdx.x * N_NODES;
    for (int n = threadIdx.x; n < N_NODES; n += 256)
        out[n] = (h[n >> 3] >> (4 * (n & 7))) & 0xF;
}

// per-node scan across chunks: baseG[b][n] = sum_{b'<b} histG[b'][n]; counts[n]=deg
__global__ void blockscan_k(const unsigned char* __restrict__ histG,
                            unsigned char* __restrict__ baseG, int* __restrict__ counts) {
    int n = blockIdx.x * 256 + threadIdx.x;
    if (n >= N_NODES) return;
    int tot = 0;
    for (int b = 0; b < CBLK; b++) {
        unsigned char v = histG[(size_t)b * N_NODES + n];   // coalesced across threads
        baseG[(size_t)b * N_NODES + n] = (unsigned char)tot;
        tot += v;
    }
    counts[n] = tot;
}

__global__ void scan_block_k(const int* __restrict__ counts, int* __restrict__ offsets,
                             int* __restrict__ blocksums) {
    __shared__ int sh[1024];
    int i = blockIdx.x * 1024 + threadIdx.x;
    int v = (i < N_NODES) ? counts[i] : 0;
    sh[threadIdx.x] = v;
    __syncthreads();
    for (int off = 1; off < 1024; off <<= 1) {
        int t = (threadIdx.x >= off) ? sh[threadIdx.x - off] : 0;
        __syncthreads();
        sh[threadIdx.x] += t;
        __syncthreads();
    }
    if (i < N_NODES) offsets[i] = sh[threadIdx.x] - v;   // exclusive
    if (threadIdx.x == 1023) blocksums[blockIdx.x] = sh[1023];
}

__global__ void scan_sums_k(int* blocksums, int nb) {
    if (threadIdx.x == 0 && blockIdx.x == 0) {
        int run = 0;
        for (int b = 0; b < nb; b++) { int t = blocksums[b]; blocksums[b] = run; run += t; }
    }
}

__global__ void finalize_offsets_k(int* __restrict__ offsets,
                                   const int* __restrict__ counts,
                                   const int* __restrict__ blocksums,
                                   float* __restrict__ dinv) {
    int i = blockIdx.x * blockDim.x + threadIdx.x;
    if (i >= N_NODES) return;
    offsets[i] = offsets[i] + blocksums[i >> 10];
    dinv[i] = rsqrtf((float)(counts[i] + 1));   // +1 self loop
}

// ---------- fused: atomic-free CSR fill + gemm layer 0 ----------
// fill block b (first CBLK blocks, spread across all XCDs): rank via u4 LDS
// hist (same chunk as count_hist_k block b), pos = offsets[n]+baseG[b][n]+rank.
// No global atomics. smem: fill uses 25KB, gemm 32KB.

__global__ __launch_bounds__(256) void gemm0_fill_k(
        const float* __restrict__ X, const float* __restrict__ W,
        const float* __restrict__ dinv, __half* __restrict__ hp,
        const int* __restrict__ src, const int* __restrict__ dst,
        const int* __restrict__ offsets, const unsigned char* __restrict__ baseG,
        unsigned short* __restrict__ ssrc) {
    __shared__ __align__(16) unsigned int smem[SMEM_WORDS];   // 8192 words = 32KB
    if (blockIdx.x < CBLK) {
        int b = blockIdx.x;
        for (int i = threadIdx.x; i < HWORDS4; i += 256) smem[i] = 0;
        __syncthreads();
        int base = b * CHUNK;
        const unsigned char* myBase = baseG + (size_t)b * N_NODES;
        for (int i = threadIdx.x; i < CHUNK; i += 256) {
            int n = dst[base + i];
            int s = src[base + i];
            unsigned int old = atomicAdd(&smem[n >> 3], 1u << (4 * (n & 7)));
            int rank = (old >> (4 * (n & 7))) & 0xF;
            ssrc[offsets[n] + myBase[n] + rank] = (unsigned short)s;
        }
        return;
    }
    // ---- gemm0 ----
    int gb = blockIdx.x - CBLK;
    float* Wl = (float*)smem;
    for (int i = threadIdx.x * 4; i < DIM_IN * 64; i += 256 * 4)
        *(float4*)&Wl[i] = *(const float4*)&W[i];
    __syncthreads();
    int c4 = (threadIdx.x & 15) * 4;
    int n0 = gb * 64 + (threadIdx.x >> 4) * 4;
    if (n0 >= N_NODES) return;
    const float* zr = X + (size_t)n0 * DIM_IN;
    float4 acc0 = {0,0,0,0}, acc1 = {0,0,0,0}, acc2 = {0,0,0,0}, acc3 = {0,0,0,0};
    #pragma unroll 4
    for (int k = 0; k < DIM_IN; k += 4) {
        float4 w0 = *(float4*)&Wl[(k + 0) * 64 + c4];
        float4 w1 = *(float4*)&Wl[(k + 1) * 64 + c4];
        float4 w2 = *(float4*)&Wl[(k + 2) * 64 + c4];
        float4 w3 = *(float4*)&Wl[(k + 3) * 64 + c4];
        float4 z0 = *(const float4*)&zr[0 * DIM_IN + k];
        float4 z1 = *(const float4*)&zr[1 * DIM_IN + k];
        float4 z2 = *(const float4*)&zr[2 * DIM_IN + k];
        float4 z3 = *(const float4*)&zr[3 * DIM_IN + k];
        fma4(acc0, z0.x, w0); fma4(acc0, z0.y, w1); fma4(acc0, z0.z, w2); fma4(acc0, z0.w, w3);
        fma4(acc1, z1.x, w0); fma4(acc1, z1.y, w1); fma4(acc1, z1.z, w2); fma4(acc1, z1.w, w3);
        fma4(acc2, z2.x, w0); fma4(acc2, z2.y, w1); fma4(acc2, z2.z, w2); fma4(acc2, z2.w, w3);
        fma4(acc3, z3.x, w0); fma4(acc3, z3.y, w1); fma4(acc3, z3.z, w2); fma4(acc3, z3.w, w3);
    }
    float d0 = dinv[n0], d1 = dinv[n0 + 1], d2 = dinv[n0 + 2], d3 = dinv[n0 + 3];
    acc0.x *= d0; acc0.y *= d0; acc0.z *= d0; acc0.w *= d0;
    acc1.x *= d1; acc1.y *= d1; acc1.z *= d1; acc1.w *= d1;
    acc2.x *= d2; acc2.y *= d2; acc2.z *= d2; acc2.w *= d2;
    acc3.x *= d3; acc3.y *= d3; acc3.z *= d3; acc3.w *= d3;
    *(h4*)&hp[(size_t)(n0 + 0) * 64 + c4] = pack_h4(acc0);
    *(h4*)&hp[(size_t)(n0 + 1) * 64 + c4] = pack_h4(acc1);
    *(h4*)&hp[(size_t)(n0 + 2) * 64 + c4] = pack_h4(acc2);
    *(h4*)&hp[(size_t)(n0 + 3) * 64 + c4] = pack_h4(acc3);
}

// ---------- gemm layers 1/2: fp16 zb input + BN affine, fp16*dinv out ----------

__global__ __launch_bounds__(256) void gemm_h_k(
        const __half* __restrict__ Z, const float* __restrict__ W,
        const float* __restrict__ scale, const float* __restrict__ shift,
        const float* __restrict__ dinv, __half* __restrict__ hp) {
    __shared__ float Wl[H_DIM * 64];
    __shared__ float scl[64], shl[64];
    for (int i = threadIdx.x * 4; i < H_DIM * 64; i += 256 * 4)
        *(float4*)&Wl[i] = *(const float4*)&W[i];
    if (threadIdx.x < 64) { scl[threadIdx.x] = scale[threadIdx.x]; shl[threadIdx.x] = shift[threadIdx.x]; }
    __syncthreads();
    int c4 = (threadIdx.x & 15) * 4;
    int n0 = blockIdx.x * 64 + (threadIdx.x >> 4) * 4;
    if (n0 >= N_NODES) return;
    float4 acc0 = {0,0,0,0}, acc1 = {0,0,0,0}, acc2 = {0,0,0,0}, acc3 = {0,0,0,0};
    #pragma unroll 4
    for (int k = 0; k < H_DIM; k += 4) {
        float4 w0 = *(float4*)&Wl[(k + 0) * 64 + c4];
        float4 w1 = *(float4*)&Wl[(k + 1) * 64 + c4];
        float4 w2 = *(float4*)&Wl[(k + 2) * 64 + c4];
        float4 w3 = *(float4*)&Wl[(k + 3) * 64 + c4];
        float4 s4 = *(float4*)&scl[k];
        float4 f4 = *(float4*)&shl[k];
        #define DO_NODE(ACC, I)                                                        \
        {   h4 r = *(const h4*)&Z[(size_t)(n0 + I) * 64 + k];                          \
            float2 p = __half22float2(r.a), q = __half22float2(r.b);                   \
            float z0 = fmaf(p.x, s4.x, f4.x), z1 = fmaf(p.y, s4.y, f4.y);              \
            float z2 = fmaf(q.x, s4.z, f4.z), z3 = fmaf(q.y, s4.w, f4.w);              \
            fma4(ACC, z0, w0); fma4(ACC, z1, w1); fma4(ACC, z2, w2); fma4(ACC, z3, w3); }
        DO_NODE(acc0, 0) DO_NODE(acc1, 1) DO_NODE(acc2, 2) DO_NODE(acc3, 3)
        #undef DO_NODE
    }
    float d0 = dinv[n0], d1 = dinv[n0 + 1], d2 = dinv[n0 + 2], d3 = dinv[n0 + 3];
    acc0.x *= d0; acc0.y *= d0; acc0.z *= d0; acc0.w *= d0;
    acc1.x *= d1; acc1.y *= d1; acc1.z *= d1; acc1.w *= d1;
    acc2.x *= d2; acc2.y *= d2; acc2.z *= d2; acc2.w *= d2;
    acc3.x *= d3; acc3.y *= d3; acc3.z *= d3; acc3.w *= d3;
    *(h4*)&hp[(size_t)(n0 + 0) * 64 + c4] = pack_h4(acc0);
    *(h4*)&hp[(size_t)(n0 + 1) * 64 + c4] = pack_h4(acc1);
    *(h4*)&hp[(size_t)(n0 + 2) * 64 + c4] = pack_h4(acc2);
    *(h4*)&hp[(size_t)(n0 + 3) * 64 + c4] = pack_h4(acc3);
}

// ---------- aggregate + relu (pure gather, x2 edge ILP) ----------

__global__ __launch_bounds__(256) void aggregate_k(
        const __half* __restrict__ hp, const float* __restrict__ dinv,
        const int* __restrict__ offsets, const int* __restrict__ counts,
        const unsigned short* __restrict__ ssrc, const float* __restrict__ bias,
        __half* __restrict__ zb) {
    int wid = (blockIdx.x * blockDim.x + threadIdx.x) >> 6;   // node (grid exact)
    int lane = threadIdx.x & 63;
    int g = lane >> 3;            // edge sub-slot 0..7
    int c8 = (lane & 7) * 8;      // channel base
    float a0=0,a1=0,a2=0,a3=0,a4=0,a5=0,a6=0,a7=0;
    int s0 = offsets[wid];
    int ce = counts[wid];
    int e = g;
    for (; e + 8 < ce; e += 16) {
        int s1 = ssrc[s0 + e];
        int s2 = ssrc[s0 + e + 8];
        h8 v1 = *(const h8*)(hp + (size_t)s1 * 64 + c8);
        h8 v2 = *(const h8*)(hp + (size_t)s2 * 64 + c8);
        float2 f0 = __half22float2(v1.a), f1 = __half22float2(v1.b);
        float2 f2 = __half22float2(v1.c), f3 = __half22float2(v1.d);
        float2 g0 = __half22float2(v2.a), g1 = __half22float2(v2.b);
        float2 g2 = __half22float2(v2.c), g3 = __half22float2(v2.d);
        a0 += f0.x + g0.x; a1 += f0.y + g0.y; a2 += f1.x + g1.x; a3 += f1.y + g1.y;
        a4 += f2.x + g2.x; a5 += f2.y + g2.y; a6 += f3.x + g3.x; a7 += f3.y + g3.y;
    }
    if (e < ce) {
        int s = ssrc[s0 + e];
        h8 v = *(const h8*)(hp + (size_t)s * 64 + c8);
        float2 f0 = __half22float2(v.a), f1 = __half22float2(v.b);
        float2 f2 = __half22float2(v.c), f3 = __half22float2(v.d);
        a0 += f0.x; a1 += f0.y; a2 += f1.x; a3 += f1.y;
        a4 += f2.x; a5 += f2.y; a6 += f3.x; a7 += f3.y;
    }
    #define RED(A) A += __shfl_xor(A, 8); A += __shfl_xor(A, 16); A += __shfl_xor(A, 32);
    RED(a0) RED(a1) RED(a2) RED(a3) RED(a4) RED(a5) RED(a6) RED(a7)
    #undef RED
    if (g == 0) {
        h8 sv = *(const h8*)(hp + (size_t)wid * 64 + c8);
        float2 f0 = __half22float2(sv.a), f1 = __half22float2(sv.b);
        float2 f2 = __half22float2(sv.c), f3 = __half22float2(sv.d);
        float di = dinv[wid];
        float4 b0 = *(const float4*)&bias[c8];
        float4 b1 = *(const float4*)&bias[c8 + 4];
        float o0 = fmaxf(fmaf(a0 + f0.x, di, b0.x), 0.f);
        float o1 = fmaxf(fmaf(a1 + f0.y, di, b0.y), 0.f);
        float o2 = fmaxf(fmaf(a2 + f1.x, di, b0.z), 0.f);
        float o3 = fmaxf(fmaf(a3 + f1.y, di, b0.w), 0.f);
        float o4 = fmaxf(fmaf(a4 + f2.x, di, b1.x), 0.f);
        float o5 = fmaxf(fmaf(a5 + f2.y, di, b1.y), 0.f);
        float o6 = fmaxf(fmaf(a6 + f3.x, di, b1.z), 0.f);
        float o7 = fmaxf(fmaf(a7 + f3.y, di, b1.w), 0.f);
        h8 ov;
        ov.a = __float22half2_rn(make_float2(o0, o1));
        ov.b = __float22half2_rn(make_float2(o2, o3));
        ov.c = __float22half2_rn(make_float2(o4, o5));
        ov.d = __float22half2_rn(make_float2(o6, o7));
        *(h8*)(zb + (size_t)wid * 64 + c8) = ov;
    }
}

// ---------- BN stats: streaming over zb, 8 replica slots ----------

__global__ __launch_bounds__(256) void bn_stats_k(const __half* __restrict__ zb,
                                                  float* __restrict__ slots) {
    int slot = threadIdx.x & 7;      // channel octet
    int rp = threadIdx.x >> 3;       // row phase 0..31
    float s[8], q[8];
    #pragma unroll
    for (int j = 0; j < 8; j++) { s[j] = 0.f; q[j] = 0.f; }
    for (int n = blockIdx.x * 32 + rp; n < N_NODES; n += 256 * 32) {
        h8 v = *(const h8*)(zb + (size_t)n * 64 + slot * 8);
        float2 f0 = __half22float2(v.a), f1 = __half22float2(v.b);
        float2 f2 = __half22float2(v.c), f3 = __half22float2(v.d);
        float x0 = f0.x, x1 = f0.y, x2 = f1.x, x3 = f1.y;
        float x4 = f2.x, x5 = f2.y, x6 = f3.x, x7 = f3.y;
        s[0] += x0; q[0] += x0 * x0; s[1] += x1; q[1] += x1 * x1;
        s[2] += x2; q[2] += x2 * x2; s[3] += x3; q[3] += x3 * x3;
        s[4] += x4; q[4] += x4 * x4; s[5] += x5; q[5] += x5 * x5;
        s[6] += x6; q[6] += x6 * x6; s[7] += x7; q[7] += x7 * x7;
    }
    #pragma unroll
    for (int j = 0; j < 8; j++) {
        float a = s[j];
        a += __shfl_xor(a, 8); a += __shfl_xor(a, 16); a += __shfl_xor(a, 32);
        s[j] = a;
        float b = q[j];
        b += __shfl_xor(b, 8); b += __shfl_xor(b, 16); b += __shfl_xor(b, 32);
        q[j] = b;
    }
    __shared__ float rs[4][64], rq[4][64];
    int w = threadIdx.x >> 6;
    if ((threadIdx.x & 63) < 8) {
        #pragma unroll
        for (int j = 0; j < 8; j++) {
            rs[w][slot * 8 + j] = s[j];
            rq[w][slot * 8 + j] = q[j];
        }
    }
    __syncthreads();
    int t = threadIdx.x;
    int rep = (blockIdx.x & 7) * 128;
    if (t < 64)
        atomicAdd(&slots[rep + t], rs[0][t] + rs[1][t] + rs[2][t] + rs[3][t]);
    else if (t < 128) {
        int c = t - 64;
        atomicAdd(&slots[rep + t], rq[0][c] + rq[1][c] + rq[2][c] + rq[3][c]);
    }
}

// reduce 8 replica slots -> scale/shift, then re-zero slots for next layer
__global__ void bn_finalize_k(float* __restrict__ slots,
                              const float* __restrict__ gamma, const float* __restrict__ beta,
                              float* __restrict__ scale, float* __restrict__ shift) {
    __shared__ float red[128];
    int c = threadIdx.x;   // 0..127
    float v = 0.f;
    #pragma unroll
    for (int r = 0; r < 8; r++) v += slots[r * 128 + c];
    red[c] = v;
    __syncthreads();
    if (c < 64) {
        float mu = red[c] * (1.0f / N_NODES);
        float var = red[c + 64] * (1.0f / N_NODES) - mu * mu;
        float k = gamma[c] * rsqrtf(var + EPS_BN);
        scale[c] = k;
        shift[c] = beta[c] - mu * k;
    }
    #pragma unroll
    for (int i = 0; i < 8; i++) slots[i * 128 + c] = 0.f;
}

// ---------- epilogue ----------

__global__ __launch_bounds__(256) void pool_k(
        const __half* __restrict__ zb0, const __half* __restrict__ zb1,
        const __half* __restrict__ zb2,
        const float* __restrict__ scaleAll, const float* __restrict__ shiftAll,
        const int* __restrict__ batch, float* __restrict__ gc) {
    int g = blockIdx.x;
    int lo = 0, hi = N_NODES;
    while (lo < hi) { int mid = (lo + hi) >> 1; if (batch[mid] < g) lo = mid + 1; else hi = mid; }
    int start = lo;
    hi = N_NODES;
    while (lo < hi) { int mid = (lo + hi) >> 1; if (batch[mid] < g + 1) lo = mid + 1; else hi = mid; }
    int end = lo;

    int slot = threadIdx.x & 7;
    int r = threadIdx.x >> 3;        // 0..31
    const __half* zbs[3] = {zb0, zb1, zb2};
    float acc[3][8];
    #pragma unroll
    for (int l = 0; l < 3; l++)
        #pragma unroll
        for (int j = 0; j < 8; j++) acc[l][j] = 0.f;
    #pragma unroll
    for (int l = 0; l < 3; l++) {
        const __half* z = zbs[l];
        for (int n = start + r; n < end; n += 32) {
            h8 v = *(const h8*)(z + (size_t)n * 64 + slot * 8);
            float2 f0 = __half22float2(v.a), f1 = __half22float2(v.b);
            float2 f2 = __half22float2(v.c), f3 = __half22float2(v.d);
            acc[l][0] += f0.x; acc[l][1] += f0.y; acc[l][2] += f1.x; acc[l][3] += f1.y;
            acc[l][4] += f2.x; acc[l][5] += f2.y; acc[l][6] += f3.x; acc[l][7] += f3.y;
        }
    }
    #pragma unroll
    for (int l = 0; l < 3; l++)
        #pragma unroll
        for (int j = 0; j < 8; j++) {
            float a = acc[l][j];
            a += __shfl_xor(a, 8);
            a += __shfl_xor(a, 16);
            a += __shfl_xor(a, 32);
            acc[l][j] = a;
        }
    __shared__ float red[4][3][64];
    int w = threadIdx.x >> 6;
    if ((threadIdx.x & 63) < 8) {
        #pragma unroll
        for (int l = 0; l < 3; l++)
            #pragma unroll
            for (int j = 0; j < 8; j++)
                red[w][l][slot * 8 + j] = acc[l][j];
    }
    __syncthreads();
    __shared__ float part[4];
    int t = threadIdx.x;
    float m = 0.f;
    if (t < 192) {
        int l = t >> 6, ch = t & 63;
        float s = red[0][l][ch] + red[1][l][ch] + red[2][l][ch] + red[3][l][ch];
        m = (end > start) ? fmaf(scaleAll[t], s / (float)(end - start), shiftAll[t]) : 0.f;
    }
    float q = m * m;
    #pragma unroll
    for (int off = 32; off; off >>= 1) q += __shfl_xor(q, off);
    if ((t & 63) == 0) part[t >> 6] = q;
    __syncthreads();
    float inv = 1.0f / fmaxf(sqrtf(part[0] + part[1] + part[2] + part[3]), 1e-12f);
    if (t < 192) gc[(size_t)g * 192 + t] = m * inv;
}

__global__ __launch_bounds__(256) void l2norm_zc_k(
        const __half* __restrict__ zb0, const __half* __restrict__ zb1,
        const __half* __restrict__ zb2,
        const float* __restrict__ scaleAll, const float* __restrict__ shiftAll,
        float* __restrict__ zc) {
    int wid = (blockIdx.x * blockDim.x + threadIdx.x) >> 6;
    int lane = threadIdx.x & 63;
    float a = fmaf(__half2float(zb0[(size_t)wid * 64 + lane]), scaleAll[lane],       shiftAll[lane]);
    float b = fmaf(__half2float(zb1[(size_t)wid * 64 + lane]), scaleAll[64 + lane],  shiftAll[64 + lane]);
    float c = fmaf(__half2float(zb2[(size_t)wid * 64 + lane]), scaleAll[128 + lane], shiftAll[128 + lane]);
    float s = a * a + b * b + c * c;
    #pragma unroll
    for (int off = 32; off; off >>= 1) s += __shfl_xor(s, off);
    float inv = 1.0f / fmaxf(sqrtf(s), 1e-12f);
    float* row = zc + (size_t)wid * 192;
    row[lane] = a * inv; row[lane + 64] = b * inv; row[lane + 128] = c * inv;
}

// ---------- launch ----------

extern "C" void kernel_launch(void* const* d_in, const int* in_sizes, int n_in,
                              void* d_out, int out_size, void* d_ws, size_t ws_size,
                              hipStream_t stream) {
    const float* x     = (const float*)d_in[0];
    const int*   ei    = (const int*)d_in[1];
    const int*   batch = (const int*)d_in[2];
    const float* W[3]     = {(const float*)d_in[3],  (const float*)d_in[7],  (const float*)d_in[11]};
    const float* bias[3]  = {(const float*)d_in[4],  (const float*)d_in[8],  (const float*)d_in[12]};
    const float* gamma[3] = {(const float*)d_in[5],  (const float*)d_in[9],  (const float*)d_in[13]};
    const float* beta[3]  = {(const float*)d_in[6],  (const float*)d_in[10], (const float*)d_in[14]};
    const int* src = ei;
    const int* dst = ei + N_EDGES;

    float* out = (float*)d_out;
    float* zc = out;                                // [N, 192]
    float* gc = out + (size_t)N_NODES * 192;        // [G, 192]

    char* w = (char*)d_ws;
    auto alloc = [&](size_t bytes) -> void* {
        void* p = (void*)w;
        w += (bytes + 255) / 256 * 256;
        return p;
    };
    int*            counts    = (int*)alloc(N_NODES * 4);
    int*            offsets   = (int*)alloc(N_NODES * 4);
    int*            blocksums = (int*)alloc(64 * 4);
    float*          dinv      = (float*)alloc(N_NODES * 4);
    unsigned short* ssrc      = (unsigned short*)alloc(N_EDGES * 2);
    __half*         hp        = (__half*)alloc((size_t)N_NODES * 64 * 2);
    __half*         zb[3];
    zb[0] = (__half*)alloc((size_t)N_NODES * 64 * 2);
    zb[1] = (__half*)alloc((size_t)N_NODES * 64 * 2);
    zb[2] = (__half*)alloc((size_t)N_NODES * 64 * 2);
    float*          slots     = (float*)alloc(8 * 128 * 4);
    float*          scaleAll  = (float*)alloc(192 * 4);
    float*          shiftAll  = (float*)alloc(192 * 4);
    // histG overlays zb[1], baseG overlays zb[2] (each CBLK*N_NODES u8 = 6.4MB).
    // Strictly sequential lifetimes; fully rewritten every call (replay-safe).
    unsigned char* histG = (unsigned char*)zb[1];
    unsigned char* baseG = (unsigned char*)zb[2];

    const int nscan = (N_NODES + 1023) / 1024;   // 49

    hipMemsetAsync(slots, 0, 8 * 128 * 4, stream);
    count_hist_k<<<CBLK, 256, 0, stream>>>(dst, histG);
    blockscan_k<<<(N_NODES + 255) / 256, 256, 0, stream>>>(histG, baseG, counts);
    scan_block_k<<<nscan, 1024, 0, stream>>>(counts, offsets, blocksums);
    scan_sums_k<<<1, 64, 0, stream>>>(blocksums, nscan);
    finalize_offsets_k<<<(N_NODES + 255) / 256, 256, 0, stream>>>(offsets, counts, blocksums, dinv);

    gemm0_fill_k<<<CBLK + GEMM0_BLOCKS, 256, 0, stream>>>(x, W[0], dinv, hp,
                                                          src, dst, offsets, baseG, ssrc);

    const int aggBlocks = N_NODES / 4;   // 12500, exact

    for (int l = 0; l < 3; l++) {
        if (l > 0)
            gemm_h_k<<<GEMM0_BLOCKS, 256, 0, stream>>>(zb[l - 1], W[l],
                                                       scaleAll + (l - 1) * 64, shiftAll + (l - 1) * 64,
                                                       dinv, hp);
        aggregate_k<<<aggBlocks, 256, 0, stream>>>(hp, dinv, offsets, counts, ssrc,
                                                   bias[l], zb[l]);
        bn_stats_k<<<256, 256, 0, stream>>>(zb[l], slots);
        bn_finalize_k<<<1, 128, 0, stream>>>(slots, gamma[l], beta[l],
                                             scaleAll + l * 64, shiftAll + l * 64);
    }

    pool_k<<<N_GRAPHS, 256, 0, stream>>>(zb[0], zb[1], zb[2], scaleAll, shiftAll, batch, gc);
    l2norm_zc_k<<<N_NODES / 4, 256, 0, stream>>>(zb[0], zb[1], zb[2], scaleAll, shiftAll, zc);
}

// Round 13
// 204.723 us; speedup vs baseline: 1.4117x; 1.1026x over previous
//
#include <hip/hip_runtime.h>
#include <hip/hip_fp16.h>
#include <cstdint>
#include <cstddef>

#define N_NODES 50000
#define N_EDGES 800000
#define DIM_IN 128
#define H_DIM 64
#define N_GRAPHS 256
#define EPS_BN 1e-5f
#define GEMM0_BLOCKS 782     // ceil(50000/64)
#define NC 128               // edge chunks
#define CHUNK 6250           // 800000 / 128
#define NB 256               // dst buckets
#define BUCKET_NODES 196     // 196*255=49980; bucket 255 holds 20 nodes
#define LSS_CAP 4096         // LDS ssrc stage (expected ~3128 +- 56)
#define SMEM_WORDS (DIM_IN * 64)   // 32KB (gemm0 Wl)

struct __align__(16) h8 { __half2 a, b, c, d; };
struct __align__(8)  h4 { __half2 a, b; };

__device__ inline void fma4(float4& a, float s, const float4& w) {
    a.x = fmaf(s, w.x, a.x);
    a.y = fmaf(s, w.y, a.y);
    a.z = fmaf(s, w.z, a.z);
    a.w = fmaf(s, w.w, a.w);
}

__device__ inline h4 pack_h4(float4 v) {
    h4 r;
    r.a = __float22half2_rn(make_float2(v.x, v.y));
    r.b = __float22half2_rn(make_float2(v.z, v.w));
    return r;
}

// ---------- k1: fused bucket-count + gemm layer 0 (UNSCALED hraw out) ----------

__global__ __launch_bounds__(256) void cnt_gemm0_k(
        const float* __restrict__ X, const float* __restrict__ W,
        __half* __restrict__ hp, const int* __restrict__ dst,
        int* __restrict__ cntM) {
    __shared__ __align__(16) unsigned int smem[SMEM_WORDS];
    if (blockIdx.x < NC) {
        int* cl = (int*)smem;
        if (threadIdx.x < NB) cl[threadIdx.x] = 0;
        __syncthreads();
        int base = blockIdx.x * CHUNK;
        for (int i = threadIdx.x; i < CHUNK; i += 256) {
            int n = dst[base + i];
            atomicAdd(&cl[n / BUCKET_NODES], 1);
        }
        __syncthreads();
        if (threadIdx.x < NB) cntM[blockIdx.x * NB + threadIdx.x] = cl[threadIdx.x];
        return;
    }
    // ---- gemm0: hraw = X @ W (no dinv scaling) ----
    int gb = blockIdx.x - NC;
    float* Wl = (float*)smem;
    for (int i = threadIdx.x * 4; i < DIM_IN * 64; i += 256 * 4)
        *(float4*)&Wl[i] = *(const float4*)&W[i];
    __syncthreads();
    int c4 = (threadIdx.x & 15) * 4;
    int n0 = gb * 64 + (threadIdx.x >> 4) * 4;
    if (n0 >= N_NODES) return;
    const float* zr = X + (size_t)n0 * DIM_IN;
    float4 acc0 = {0,0,0,0}, acc1 = {0,0,0,0}, acc2 = {0,0,0,0}, acc3 = {0,0,0,0};
    #pragma unroll 4
    for (int k = 0; k < DIM_IN; k += 4) {
        float4 w0 = *(float4*)&Wl[(k + 0) * 64 + c4];
        float4 w1 = *(float4*)&Wl[(k + 1) * 64 + c4];
        float4 w2 = *(float4*)&Wl[(k + 2) * 64 + c4];
        float4 w3 = *(float4*)&Wl[(k + 3) * 64 + c4];
        float4 z0 = *(const float4*)&zr[0 * DIM_IN + k];
        float4 z1 = *(const float4*)&zr[1 * DIM_IN + k];
        float4 z2 = *(const float4*)&zr[2 * DIM_IN + k];
        float4 z3 = *(const float4*)&zr[3 * DIM_IN + k];
        fma4(acc0, z0.x, w0); fma4(acc0, z0.y, w1); fma4(acc0, z0.z, w2); fma4(acc0, z0.w, w3);
        fma4(acc1, z1.x, w0); fma4(acc1, z1.y, w1); fma4(acc1, z1.z, w2); fma4(acc1, z1.w, w3);
        fma4(acc2, z2.x, w0); fma4(acc2, z2.y, w1); fma4(acc2, z2.z, w2); fma4(acc2, z2.w, w3);
        fma4(acc3, z3.x, w0); fma4(acc3, z3.y, w1); fma4(acc3, z3.z, w2); fma4(acc3, z3.w, w3);
    }
    *(h4*)&hp[(size_t)(n0 + 0) * 64 + c4] = pack_h4(acc0);
    *(h4*)&hp[(size_t)(n0 + 1) * 64 + c4] = pack_h4(acc1);
    *(h4*)&hp[(size_t)(n0 + 2) * 64 + c4] = pack_h4(acc2);
    *(h4*)&hp[(size_t)(n0 + 3) * 64 + c4] = pack_h4(acc3);
}

// ---------- k2: scan cntM -> baseM (per chunk,bucket) + beb (bucket edge base) ----------

__global__ void scanM_k(const int* __restrict__ cntM, int* __restrict__ baseM,
                        int* __restrict__ beb) {
    __shared__ int colsum[NB];
    int w = threadIdx.x;   // 256
    int tot = 0;
    for (int c = 0; c < NC; c++) {
        baseM[c * NB + w] = tot;
        tot += cntM[c * NB + w];
    }
    colsum[w] = tot;
    __syncthreads();
    if (w == 0) {
        int run = 0;
        for (int b = 0; b < NB; b++) { beb[b] = run; run += colsum[b]; }
        beb[NB] = run;   // == N_EDGES
    }
}

// ---------- k3: scatter edges into dense per-bucket runs (line-friendly) ----------

__global__ __launch_bounds__(256) void scatter_k(
        const int* __restrict__ src, const int* __restrict__ dst,
        const int* __restrict__ baseM, const int* __restrict__ beb,
        unsigned int* __restrict__ ebuf) {
    __shared__ int rk[NB];
    int c = blockIdx.x;
    if (threadIdx.x < NB) rk[threadIdx.x] = 0;
    __syncthreads();
    int base = c * CHUNK;
    for (int i = threadIdx.x; i < CHUNK; i += 256) {
        int n = dst[base + i];
        int s = src[base + i];
        int w = n / BUCKET_NODES;
        int r = atomicAdd(&rk[w], 1);
        ebuf[beb[w] + baseM[c * NB + w] + r] = ((unsigned)n << 16) | (unsigned)s;
    }
}

// ---------- k4: per-bucket CSR finalize: counts/offsets/dinv + LDS-staged ssrc ----------

__global__ __launch_bounds__(256) void fill_k(
        const unsigned int* __restrict__ ebuf, const int* __restrict__ beb,
        int* __restrict__ counts, int* __restrict__ offsets, float* __restrict__ dinv,
        unsigned short* __restrict__ ssrc) {
    int w = blockIdx.x;
    int n0 = w * BUCKET_NODES;
    int nn = min(BUCKET_NODES, N_NODES - n0);
    int eb = beb[w];
    int ec = beb[w + 1] - eb;
    __shared__ int cnt[BUCKET_NODES];
    __shared__ int sc[NB];
    __shared__ unsigned short lssrc[LSS_CAP];
    int t = threadIdx.x;
    if (t < BUCKET_NODES) cnt[t] = 0;
    __syncthreads();
    for (int i = t; i < ec; i += 256) {
        int nl = (int)(ebuf[eb + i] >> 16) - n0;
        atomicAdd(&cnt[nl], 1);
    }
    __syncthreads();
    int cj = (t < nn) ? cnt[t] : 0;
    sc[t] = cj;
    __syncthreads();
    for (int off = 1; off < NB; off <<= 1) {   // inclusive Hillis-Steele
        int a = (t >= off) ? sc[t - off] : 0;
        __syncthreads();
        sc[t] += a;
        __syncthreads();
    }
    int offj = sc[t] - cj;   // exclusive
    if (t < nn) {
        int n = n0 + t;
        counts[n] = cj;
        offsets[n] = eb + offj;
        dinv[n] = rsqrtf((float)(cj + 1));
        cnt[t] = offj;       // becomes cursor
    }
    __syncthreads();
    for (int i = t; i < ec; i += 256) {
        unsigned int e = ebuf[eb + i];
        int nl = (int)(e >> 16) - n0;
        int p = atomicAdd(&cnt[nl], 1);
        unsigned short s = (unsigned short)(e & 0xffffu);
        if (p < LSS_CAP) lssrc[p] = s;
        else ssrc[eb + p] = s;   // pathological overflow only
    }
    __syncthreads();
    int lim = min(ec, LSS_CAP);
    for (int i = t; i < lim; i += 256) ssrc[eb + i] = lssrc[i];   // coalesced
}

// ---------- gemm layers 1/2: fp16 zb input + BN affine, UNSCALED hraw out ----------

__global__ __launch_bounds__(256) void gemm_h_k(
        const __half* __restrict__ Z, const float* __restrict__ W,
        const float* __restrict__ scale, const float* __restrict__ shift,
        __half* __restrict__ hp) {
    __shared__ float Wl[H_DIM * 64];
    __shared__ float scl[64], shl[64];
    for (int i = threadIdx.x * 4; i < H_DIM * 64; i += 256 * 4)
        *(float4*)&Wl[i] = *(const float4*)&W[i];
    if (threadIdx.x < 64) { scl[threadIdx.x] = scale[threadIdx.x]; shl[threadIdx.x] = shift[threadIdx.x]; }
    __syncthreads();
    int c4 = (threadIdx.x & 15) * 4;
    int n0 = blockIdx.x * 64 + (threadIdx.x >> 4) * 4;
    if (n0 >= N_NODES) return;
    float4 acc0 = {0,0,0,0}, acc1 = {0,0,0,0}, acc2 = {0,0,0,0}, acc3 = {0,0,0,0};
    #pragma unroll 4
    for (int k = 0; k < H_DIM; k += 4) {
        float4 w0 = *(float4*)&Wl[(k + 0) * 64 + c4];
        float4 w1 = *(float4*)&Wl[(k + 1) * 64 + c4];
        float4 w2 = *(float4*)&Wl[(k + 2) * 64 + c4];
        float4 w3 = *(float4*)&Wl[(k + 3) * 64 + c4];
        float4 s4 = *(float4*)&scl[k];
        float4 f4 = *(float4*)&shl[k];
        #define DO_NODE(ACC, I)                                                        \
        {   h4 r = *(const h4*)&Z[(size_t)(n0 + I) * 64 + k];                          \
            float2 p = __half22float2(r.a), q = __half22float2(r.b);                   \
            float z0 = fmaf(p.x, s4.x, f4.x), z1 = fmaf(p.y, s4.y, f4.y);              \
            float z2 = fmaf(q.x, s4.z, f4.z), z3 = fmaf(q.y, s4.w, f4.w);              \
            fma4(ACC, z0, w0); fma4(ACC, z1, w1); fma4(ACC, z2, w2); fma4(ACC, z3, w3); }
        DO_NODE(acc0, 0) DO_NODE(acc1, 1) DO_NODE(acc2, 2) DO_NODE(acc3, 3)
        #undef DO_NODE
    }
    *(h4*)&hp[(size_t)(n0 + 0) * 64 + c4] = pack_h4(acc0);
    *(h4*)&hp[(size_t)(n0 + 1) * 64 + c4] = pack_h4(acc1);
    *(h4*)&hp[(size_t)(n0 + 2) * 64 + c4] = pack_h4(acc2);
    *(h4*)&hp[(size_t)(n0 + 3) * 64 + c4] = pack_h4(acc3);
}

// ---------- aggregate + relu (per-edge dinv[src], x2 edge ILP) ----------
// z = relu((sum_e hraw[s]*dinv[s] + hraw[i]*dinv[i]) * dinv[i] + bias)

__global__ __launch_bounds__(256) void aggregate_k(
        const __half* __restrict__ hp, const float* __restrict__ dinv,
        const int* __restrict__ offsets, const int* __restrict__ counts,
        const unsigned short* __restrict__ ssrc, const float* __restrict__ bias,
        __half* __restrict__ zb) {
    int wid = (blockIdx.x * blockDim.x + threadIdx.x) >> 6;   // node (grid exact)
    int lane = threadIdx.x & 63;
    int g = lane >> 3;            // edge sub-slot 0..7
    int c8 = (lane & 7) * 8;      // channel base
    float a0=0,a1=0,a2=0,a3=0,a4=0,a5=0,a6=0,a7=0;
    int s0 = offsets[wid];
    int ce = counts[wid];
    int e = g;
    for (; e + 8 < ce; e += 16) {
        int s1 = ssrc[s0 + e];
        int s2 = ssrc[s0 + e + 8];
        float d1 = dinv[s1], d2 = dinv[s2];
        h8 v1 = *(const h8*)(hp + (size_t)s1 * 64 + c8);
        h8 v2 = *(const h8*)(hp + (size_t)s2 * 64 + c8);
        float2 f0 = __half22float2(v1.a), f1 = __half22float2(v1.b);
        float2 f2 = __half22float2(v1.c), f3 = __half22float2(v1.d);
        float2 g0 = __half22float2(v2.a), g1 = __half22float2(v2.b);
        float2 g2 = __half22float2(v2.c), g3 = __half22float2(v2.d);
        a0 = fmaf(f0.x, d1, a0); a0 = fmaf(g0.x, d2, a0);
        a1 = fmaf(f0.y, d1, a1); a1 = fmaf(g0.y, d2, a1);
        a2 = fmaf(f1.x, d1, a2); a2 = fmaf(g1.x, d2, a2);
        a3 = fmaf(f1.y, d1, a3); a3 = fmaf(g1.y, d2, a3);
        a4 = fmaf(f2.x, d1, a4); a4 = fmaf(g2.x, d2, a4);
        a5 = fmaf(f2.y, d1, a5); a5 = fmaf(g2.y, d2, a5);
        a6 = fmaf(f3.x, d1, a6); a6 = fmaf(g3.x, d2, a6);
        a7 = fmaf(f3.y, d1, a7); a7 = fmaf(g3.y, d2, a7);
    }
    if (e < ce) {
        int s = ssrc[s0 + e];
        float d1 = dinv[s];
        h8 v = *(const h8*)(hp + (size_t)s * 64 + c8);
        float2 f0 = __half22float2(v.a), f1 = __half22float2(v.b);
        float2 f2 = __half22float2(v.c), f3 = __half22float2(v.d);
        a0 = fmaf(f0.x, d1, a0); a1 = fmaf(f0.y, d1, a1);
        a2 = fmaf(f1.x, d1, a2); a3 = fmaf(f1.y, d1, a3);
        a4 = fmaf(f2.x, d1, a4); a5 = fmaf(f2.y, d1, a5);
        a6 = fmaf(f3.x, d1, a6); a7 = fmaf(f3.y, d1, a7);
    }
    #define RED(A) A += __shfl_xor(A, 8); A += __shfl_xor(A, 16); A += __shfl_xor(A, 32);
    RED(a0) RED(a1) RED(a2) RED(a3) RED(a4) RED(a5) RED(a6) RED(a7)
    #undef RED
    if (g == 0) {
        h8 sv = *(const h8*)(hp + (size_t)wid * 64 + c8);
        float2 f0 = __half22float2(sv.a), f1 = __half22float2(sv.b);
        float2 f2 = __half22float2(sv.c), f3 = __half22float2(sv.d);
        float di = dinv[wid];
        float4 b0 = *(const float4*)&bias[c8];
        float4 b1 = *(const float4*)&bias[c8 + 4];
        float o0 = fmaxf(fmaf(fmaf(f0.x, di, a0), di, b0.x), 0.f);
        float o1 = fmaxf(fmaf(fmaf(f0.y, di, a1), di, b0.y), 0.f);
        float o2 = fmaxf(fmaf(fmaf(f1.x, di, a2), di, b0.z), 0.f);
        float o3 = fmaxf(fmaf(fmaf(f1.y, di, a3), di, b0.w), 0.f);
        float o4 = fmaxf(fmaf(fmaf(f2.x, di, a4), di, b1.x), 0.f);
        float o5 = fmaxf(fmaf(fmaf(f2.y, di, a5), di, b1.y), 0.f);
        float o6 = fmaxf(fmaf(fmaf(f3.x, di, a6), di, b1.z), 0.f);
        float o7 = fmaxf(fmaf(fmaf(f3.y, di, a7), di, b1.w), 0.f);
        h8 ov;
        ov.a = __float22half2_rn(make_float2(o0, o1));
        ov.b = __float22half2_rn(make_float2(o2, o3));
        ov.c = __float22half2_rn(make_float2(o4, o5));
        ov.d = __float22half2_rn(make_float2(o6, o7));
        *(h8*)(zb + (size_t)wid * 64 + c8) = ov;
    }
}

// ---------- BN stats: streaming over zb, 8 replica slots ----------

__global__ __launch_bounds__(256) void bn_stats_k(const __half* __restrict__ zb,
                                                  float* __restrict__ slots) {
    int slot = threadIdx.x & 7;
    int rp = threadIdx.x >> 3;
    float s[8], q[8];
    #pragma unroll
    for (int j = 0; j < 8; j++) { s[j] = 0.f; q[j] = 0.f; }
    for (int n = blockIdx.x * 32 + rp; n < N_NODES; n += 256 * 32) {
        h8 v = *(const h8*)(zb + (size_t)n * 64 + slot * 8);
        float2 f0 = __half22float2(v.a), f1 = __half22float2(v.b);
        float2 f2 = __half22float2(v.c), f3 = __half22float2(v.d);
        float x0 = f0.x, x1 = f0.y, x2 = f1.x, x3 = f1.y;
        float x4 = f2.x, x5 = f2.y, x6 = f3.x, x7 = f3.y;
        s[0] += x0; q[0] += x0 * x0; s[1] += x1; q[1] += x1 * x1;
        s[2] += x2; q[2] += x2 * x2; s[3] += x3; q[3] += x3 * x3;
        s[4] += x4; q[4] += x4 * x4; s[5] += x5; q[5] += x5 * x5;
        s[6] += x6; q[6] += x6 * x6; s[7] += x7; q[7] += x7 * x7;
    }
    #pragma unroll
    for (int j = 0; j < 8; j++) {
        float a = s[j];
        a += __shfl_xor(a, 8); a += __shfl_xor(a, 16); a += __shfl_xor(a, 32);
        s[j] = a;
        float b = q[j];
        b += __shfl_xor(b, 8); b += __shfl_xor(b, 16); b += __shfl_xor(b, 32);
        q[j] = b;
    }
    __shared__ float rs[4][64], rq[4][64];
    int w = threadIdx.x >> 6;
    if ((threadIdx.x & 63) < 8) {
        #pragma unroll
        for (int j = 0; j < 8; j++) {
            rs[w][slot * 8 + j] = s[j];
            rq[w][slot * 8 + j] = q[j];
        }
    }
    __syncthreads();
    int t = threadIdx.x;
    int rep = (blockIdx.x & 7) * 128;
    if (t < 64)
        atomicAdd(&slots[rep + t], rs[0][t] + rs[1][t] + rs[2][t] + rs[3][t]);
    else if (t < 128) {
        int c = t - 64;
        atomicAdd(&slots[rep + t], rq[0][c] + rq[1][c] + rq[2][c] + rq[3][c]);
    }
}

__global__ void bn_finalize_k(float* __restrict__ slots,
                              const float* __restrict__ gamma, const float* __restrict__ beta,
                              float* __restrict__ scale, float* __restrict__ shift) {
    __shared__ float red[128];
    int c = threadIdx.x;
    float v = 0.f;
    #pragma unroll
    for (int r = 0; r < 8; r++) v += slots[r * 128 + c];
    red[c] = v;
    __syncthreads();
    if (c < 64) {
        float mu = red[c] * (1.0f / N_NODES);
        float var = red[c + 64] * (1.0f / N_NODES) - mu * mu;
        float k = gamma[c] * rsqrtf(var + EPS_BN);
        scale[c] = k;
        shift[c] = beta[c] - mu * k;
    }
    #pragma unroll
    for (int i = 0; i < 8; i++) slots[i * 128 + c] = 0.f;
}

// ---------- epilogue ----------

__global__ __launch_bounds__(256) void pool_k(
        const __half* __restrict__ zb0, const __half* __restrict__ zb1,
        const __half* __restrict__ zb2,
        const float* __restrict__ scaleAll, const float* __restrict__ shiftAll,
        const int* __restrict__ batch, float* __restrict__ gc) {
    int g = blockIdx.x;
    int lo = 0, hi = N_NODES;
    while (lo < hi) { int mid = (lo + hi) >> 1; if (batch[mid] < g) lo = mid + 1; else hi = mid; }
    int start = lo;
    hi = N_NODES;
    while (lo < hi) { int mid = (lo + hi) >> 1; if (batch[mid] < g + 1) lo = mid + 1; else hi = mid; }
    int end = lo;

    int slot = threadIdx.x & 7;
    int r = threadIdx.x >> 3;
    const __half* zbs[3] = {zb0, zb1, zb2};
    float acc[3][8];
    #pragma unroll
    for (int l = 0; l < 3; l++)
        #pragma unroll
        for (int j = 0; j < 8; j++) acc[l][j] = 0.f;
    #pragma unroll
    for (int l = 0; l < 3; l++) {
        const __half* z = zbs[l];
        for (int n = start + r; n < end; n += 32) {
            h8 v = *(const h8*)(z + (size_t)n * 64 + slot * 8);
            float2 f0 = __half22float2(v.a), f1 = __half22float2(v.b);
            float2 f2 = __half22float2(v.c), f3 = __half22float2(v.d);
            acc[l][0] += f0.x; acc[l][1] += f0.y; acc[l][2] += f1.x; acc[l][3] += f1.y;
            acc[l][4] += f2.x; acc[l][5] += f2.y; acc[l][6] += f3.x; acc[l][7] += f3.y;
        }
    }
    #pragma unroll
    for (int l = 0; l < 3; l++)
        #pragma unroll
        for (int j = 0; j < 8; j++) {
            float a = acc[l][j];
            a += __shfl_xor(a, 8);
            a += __shfl_xor(a, 16);
            a += __shfl_xor(a, 32);
            acc[l][j] = a;
        }
    __shared__ float red[4][3][64];
    int w = threadIdx.x >> 6;
    if ((threadIdx.x & 63) < 8) {
        #pragma unroll
        for (int l = 0; l < 3; l++)
            #pragma unroll
            for (int j = 0; j < 8; j++)
                red[w][l][slot * 8 + j] = acc[l][j];
    }
    __syncthreads();
    __shared__ float part[4];
    int t = threadIdx.x;
    float m = 0.f;
    if (t < 192) {
        int l = t >> 6, ch = t & 63;
        float s = red[0][l][ch] + red[1][l][ch] + red[2][l][ch] + red[3][l][ch];
        m = (end > start) ? fmaf(scaleAll[t], s / (float)(end - start), shiftAll[t]) : 0.f;
    }
    float q = m * m;
    #pragma unroll
    for (int off = 32; off; off >>= 1) q += __shfl_xor(q, off);
    if ((t & 63) == 0) part[t >> 6] = q;
    __syncthreads();
    float inv = 1.0f / fmaxf(sqrtf(part[0] + part[1] + part[2] + part[3]), 1e-12f);
    if (t < 192) gc[(size_t)g * 192 + t] = m * inv;
}

__global__ __launch_bounds__(256) void l2norm_zc_k(
        const __half* __restrict__ zb0, const __half* __restrict__ zb1,
        const __half* __restrict__ zb2,
        const float* __restrict__ scaleAll, const float* __restrict__ shiftAll,
        float* __restrict__ zc) {
    int wid = (blockIdx.x * blockDim.x + threadIdx.x) >> 6;
    int lane = threadIdx.x & 63;
    float a = fmaf(__half2float(zb0[(size_t)wid * 64 + lane]), scaleAll[lane],       shiftAll[lane]);
    float b = fmaf(__half2float(zb1[(size_t)wid * 64 + lane]), scaleAll[64 + lane],  shiftAll[64 + lane]);
    float c = fmaf(__half2float(zb2[(size_t)wid * 64 + lane]), scaleAll[128 + lane], shiftAll[128 + lane]);
    float s = a * a + b * b + c * c;
    #pragma unroll
    for (int off = 32; off; off >>= 1) s += __shfl_xor(s, off);
    float inv = 1.0f / fmaxf(sqrtf(s), 1e-12f);
    float* row = zc + (size_t)wid * 192;
    row[lane] = a * inv; row[lane + 64] = b * inv; row[lane + 128] = c * inv;
}

// ---------- launch ----------

extern "C" void kernel_launch(void* const* d_in, const int* in_sizes, int n_in,
                              void* d_out, int out_size, void* d_ws, size_t ws_size,
                              hipStream_t stream) {
    const float* x     = (const float*)d_in[0];
    const int*   ei    = (const int*)d_in[1];
    const int*   batch = (const int*)d_in[2];
    const float* W[3]     = {(const float*)d_in[3],  (const float*)d_in[7],  (const float*)d_in[11]};
    const float* bias[3]  = {(const float*)d_in[4],  (const float*)d_in[8],  (const float*)d_in[12]};
    const float* gamma[3] = {(const float*)d_in[5],  (const float*)d_in[9],  (const float*)d_in[13]};
    const float* beta[3]  = {(const float*)d_in[6],  (const float*)d_in[10], (const float*)d_in[14]};
    const int* src = ei;
    const int* dst = ei + N_EDGES;

    float* out = (float*)d_out;
    float* zc = out;                                // [N, 192]
    float* gc = out + (size_t)N_NODES * 192;        // [G, 192]

    char* w = (char*)d_ws;
    auto alloc = [&](size_t bytes) -> void* {
        void* p = (void*)w;
        w += (bytes + 255) / 256 * 256;
        return p;
    };
    int*            counts    = (int*)alloc(N_NODES * 4);
    int*            offsets   = (int*)alloc(N_NODES * 4);
    float*          dinv      = (float*)alloc(N_NODES * 4);
    unsigned short* ssrc      = (unsigned short*)alloc(N_EDGES * 2);
    __half*         hp        = (__half*)alloc((size_t)N_NODES * 64 * 2);
    __half*         zb[3];
    zb[0] = (__half*)alloc((size_t)N_NODES * 64 * 2);
    zb[1] = (__half*)alloc((size_t)N_NODES * 64 * 2);
    zb[2] = (__half*)alloc((size_t)N_NODES * 64 * 2);
    float*          slots     = (float*)alloc(8 * 128 * 4);
    float*          scaleAll  = (float*)alloc(192 * 4);
    float*          shiftAll  = (float*)alloc(192 * 4);
    // Overlays (strictly sequential lifetimes, fully rewritten each call —
    // pattern proven in rounds 9-12):
    //   ebuf (3.2MB) on zb[1]: written k3, read k4; zb[1] first written at agg(l=1).
    //   cntM/baseM/beb (257KB) on zb[2]: written k1/k2, read k2/k3/k4;
    //   zb[2] first written at agg(l=2).
    unsigned int* ebuf  = (unsigned int*)zb[1];
    int*          cntM  = (int*)zb[2];                       // NC*NB ints = 128KB
    int*          baseM = (int*)((char*)zb[2] + NC * NB * 4);// 128KB
    int*          beb   = (int*)((char*)zb[2] + 2 * NC * NB * 4); // 257 ints

    hipMemsetAsync(slots, 0, 8 * 128 * 4, stream);
    cnt_gemm0_k<<<NC + GEMM0_BLOCKS, 256, 0, stream>>>(x, W[0], hp, dst, cntM);
    scanM_k<<<1, NB, 0, stream>>>(cntM, baseM, beb);
    scatter_k<<<NC, 256, 0, stream>>>(src, dst, baseM, beb, ebuf);
    fill_k<<<NB, 256, 0, stream>>>(ebuf, beb, counts, offsets, dinv, ssrc);

    const int aggBlocks = N_NODES / 4;   // 12500, exact

    for (int l = 0; l < 3; l++) {
        if (l > 0)
            gemm_h_k<<<GEMM0_BLOCKS, 256, 0, stream>>>(zb[l - 1], W[l],
                                                       scaleAll + (l - 1) * 64, shiftAll + (l - 1) * 64,
                                                       hp);
        aggregate_k<<<aggBlocks, 256, 0, stream>>>(hp, dinv, offsets, counts, ssrc,
                                                   bias[l], zb[l]);
        bn_stats_k<<<256, 256, 0, stream>>>(zb[l], slots);
        bn_finalize_k<<<1, 128, 0, stream>>>(slots, gamma[l], beta[l],
                                             scaleAll + l * 64, shiftAll + l * 64);
    }

    pool_k<<<N_GRAPHS, 256, 0, stream>>>(zb[0], zb[1], zb[2], scaleAll, shiftAll, batch, gc);
    l2norm_zc_k<<<N_NODES / 4, 256, 0, stream>>>(zb[0], zb[1], zb[2], scaleAll, shiftAll, zc);
}

// Round 14
// 199.841 us; speedup vs baseline: 1.4462x; 1.0244x over previous
//
#include <hip/hip_runtime.h>
#include <hip/hip_fp16.h>
#include <cstdint>
#include <cstddef>

#define N_NODES 50000
#define N_EDGES 800000
#define DIM_IN 128
#define H_DIM 64
#define N_GRAPHS 256
#define EPS_BN 1e-5f
#define GEMM0_BLOCKS 782     // ceil(50000/64)
#define NC 128               // edge chunks
#define CHUNK 6250           // 800000 / 128
#define NB 256               // dst buckets
#define BUCKET_NODES 196     // 196*255=49980; bucket 255 holds 20 nodes
#define LSS_CAP 4096         // LDS ssrc stage (expected ~3128 +- 56)
#define SMEM_WORDS (DIM_IN * 64)   // 32KB (gemm0 Wl)

struct __align__(16) h8 { __half2 a, b, c, d; };
struct __align__(8)  h4 { __half2 a, b; };

__device__ inline void fma4(float4& a, float s, const float4& w) {
    a.x = fmaf(s, w.x, a.x);
    a.y = fmaf(s, w.y, a.y);
    a.z = fmaf(s, w.z, a.z);
    a.w = fmaf(s, w.w, a.w);
}

__device__ inline h4 pack_h4(float4 v) {
    h4 r;
    r.a = __float22half2_rn(make_float2(v.x, v.y));
    r.b = __float22half2_rn(make_float2(v.z, v.w));
    return r;
}

// ---------- k1: fused bucket-count + gemm layer 0 (UNSCALED hraw out) ----------

__global__ __launch_bounds__(256) void cnt_gemm0_k(
        const float* __restrict__ X, const float* __restrict__ W,
        __half* __restrict__ hp, const int* __restrict__ dst,
        int* __restrict__ cntM) {
    __shared__ __align__(16) unsigned int smem[SMEM_WORDS];
    if (blockIdx.x < NC) {
        int* cl = (int*)smem;
        if (threadIdx.x < NB) cl[threadIdx.x] = 0;
        __syncthreads();
        int base = blockIdx.x * CHUNK;
        for (int i = threadIdx.x; i < CHUNK; i += 256) {
            int n = dst[base + i];
            atomicAdd(&cl[n / BUCKET_NODES], 1);
        }
        __syncthreads();
        if (threadIdx.x < NB) cntM[blockIdx.x * NB + threadIdx.x] = cl[threadIdx.x];
        return;
    }
    // ---- gemm0: hraw = X @ W (no dinv scaling yet) ----
    int gb = blockIdx.x - NC;
    float* Wl = (float*)smem;
    for (int i = threadIdx.x * 4; i < DIM_IN * 64; i += 256 * 4)
        *(float4*)&Wl[i] = *(const float4*)&W[i];
    __syncthreads();
    int c4 = (threadIdx.x & 15) * 4;
    int n0 = gb * 64 + (threadIdx.x >> 4) * 4;
    if (n0 >= N_NODES) return;
    const float* zr = X + (size_t)n0 * DIM_IN;
    float4 acc0 = {0,0,0,0}, acc1 = {0,0,0,0}, acc2 = {0,0,0,0}, acc3 = {0,0,0,0};
    #pragma unroll 4
    for (int k = 0; k < DIM_IN; k += 4) {
        float4 w0 = *(float4*)&Wl[(k + 0) * 64 + c4];
        float4 w1 = *(float4*)&Wl[(k + 1) * 64 + c4];
        float4 w2 = *(float4*)&Wl[(k + 2) * 64 + c4];
        float4 w3 = *(float4*)&Wl[(k + 3) * 64 + c4];
        float4 z0 = *(const float4*)&zr[0 * DIM_IN + k];
        float4 z1 = *(const float4*)&zr[1 * DIM_IN + k];
        float4 z2 = *(const float4*)&zr[2 * DIM_IN + k];
        float4 z3 = *(const float4*)&zr[3 * DIM_IN + k];
        fma4(acc0, z0.x, w0); fma4(acc0, z0.y, w1); fma4(acc0, z0.z, w2); fma4(acc0, z0.w, w3);
        fma4(acc1, z1.x, w0); fma4(acc1, z1.y, w1); fma4(acc1, z1.z, w2); fma4(acc1, z1.w, w3);
        fma4(acc2, z2.x, w0); fma4(acc2, z2.y, w1); fma4(acc2, z2.z, w2); fma4(acc2, z2.w, w3);
        fma4(acc3, z3.x, w0); fma4(acc3, z3.y, w1); fma4(acc3, z3.z, w2); fma4(acc3, z3.w, w3);
    }
    *(h4*)&hp[(size_t)(n0 + 0) * 64 + c4] = pack_h4(acc0);
    *(h4*)&hp[(size_t)(n0 + 1) * 64 + c4] = pack_h4(acc1);
    *(h4*)&hp[(size_t)(n0 + 2) * 64 + c4] = pack_h4(acc2);
    *(h4*)&hp[(size_t)(n0 + 3) * 64 + c4] = pack_h4(acc3);
}

// ---------- k2: scan cntM -> baseM + beb ----------

__global__ void scanM_k(const int* __restrict__ cntM, int* __restrict__ baseM,
                        int* __restrict__ beb) {
    __shared__ int colsum[NB];
    int w = threadIdx.x;   // 256
    int tot = 0;
    for (int c = 0; c < NC; c++) {
        baseM[c * NB + w] = tot;
        tot += cntM[c * NB + w];
    }
    colsum[w] = tot;
    __syncthreads();
    if (w == 0) {
        int run = 0;
        for (int b = 0; b < NB; b++) { beb[b] = run; run += colsum[b]; }
        beb[NB] = run;   // == N_EDGES
    }
}

// ---------- k3: scatter edges into dense per-bucket runs ----------

__global__ __launch_bounds__(256) void scatter_k(
        const int* __restrict__ src, const int* __restrict__ dst,
        const int* __restrict__ baseM, const int* __restrict__ beb,
        unsigned int* __restrict__ ebuf) {
    __shared__ int rk[NB];
    int c = blockIdx.x;
    if (threadIdx.x < NB) rk[threadIdx.x] = 0;
    __syncthreads();
    int base = c * CHUNK;
    for (int i = threadIdx.x; i < CHUNK; i += 256) {
        int n = dst[base + i];
        int s = src[base + i];
        int w = n / BUCKET_NODES;
        int r = atomicAdd(&rk[w], 1);
        ebuf[beb[w] + baseM[c * NB + w] + r] = ((unsigned)n << 16) | (unsigned)s;
    }
}

// ---------- k4: per-bucket CSR finalize ----------

__global__ __launch_bounds__(256) void fill_k(
        const unsigned int* __restrict__ ebuf, const int* __restrict__ beb,
        int* __restrict__ counts, int* __restrict__ offsets, float* __restrict__ dinv,
        unsigned short* __restrict__ ssrc) {
    int w = blockIdx.x;
    int n0 = w * BUCKET_NODES;
    int nn = min(BUCKET_NODES, N_NODES - n0);
    int eb = beb[w];
    int ec = beb[w + 1] - eb;
    __shared__ int cnt[BUCKET_NODES];
    __shared__ int sc[NB];
    __shared__ unsigned short lssrc[LSS_CAP];
    int t = threadIdx.x;
    if (t < BUCKET_NODES) cnt[t] = 0;
    __syncthreads();
    for (int i = t; i < ec; i += 256) {
        int nl = (int)(ebuf[eb + i] >> 16) - n0;
        atomicAdd(&cnt[nl], 1);
    }
    __syncthreads();
    int cj = (t < nn) ? cnt[t] : 0;
    sc[t] = cj;
    __syncthreads();
    for (int off = 1; off < NB; off <<= 1) {   // inclusive Hillis-Steele
        int a = (t >= off) ? sc[t - off] : 0;
        __syncthreads();
        sc[t] += a;
        __syncthreads();
    }
    int offj = sc[t] - cj;   // exclusive
    if (t < nn) {
        int n = n0 + t;
        counts[n] = cj;
        offsets[n] = eb + offj;
        dinv[n] = rsqrtf((float)(cj + 1));
        cnt[t] = offj;       // becomes cursor
    }
    __syncthreads();
    for (int i = t; i < ec; i += 256) {
        unsigned int e = ebuf[eb + i];
        int nl = (int)(e >> 16) - n0;
        int p = atomicAdd(&cnt[nl], 1);
        unsigned short s = (unsigned short)(e & 0xffffu);
        if (p < LSS_CAP) lssrc[p] = s;
        else ssrc[eb + p] = s;   // pathological overflow only
    }
    __syncthreads();
    int lim = min(ec, LSS_CAP);
    for (int i = t; i < lim; i += 256) ssrc[eb + i] = lssrc[i];   // coalesced
}

// ---------- k5: hp *= dinv (layer 0 post-scale; layers 1/2 scale in gemm_h) ----------

__global__ __launch_bounds__(256) void scale_hp_k(__half* __restrict__ hp,
                                                  const float* __restrict__ dinv) {
    int idx = blockIdx.x * 256 + threadIdx.x;   // unit = 8 channels
    if (idx >= N_NODES * 8) return;
    float d = dinv[idx >> 3];
    h8 v = *(h8*)(hp + (size_t)idx * 8);
    float2 f0 = __half22float2(v.a), f1 = __half22float2(v.b);
    float2 f2 = __half22float2(v.c), f3 = __half22float2(v.d);
    h8 o;
    o.a = __float22half2_rn(make_float2(f0.x * d, f0.y * d));
    o.b = __float22half2_rn(make_float2(f1.x * d, f1.y * d));
    o.c = __float22half2_rn(make_float2(f2.x * d, f2.y * d));
    o.d = __float22half2_rn(make_float2(f3.x * d, f3.y * d));
    *(h8*)(hp + (size_t)idx * 8) = o;
}

// ---------- gemm layers 1/2: fp16 zb input + BN affine, fp16*dinv out ----------

__global__ __launch_bounds__(256) void gemm_h_k(
        const __half* __restrict__ Z, const float* __restrict__ W,
        const float* __restrict__ scale, const float* __restrict__ shift,
        const float* __restrict__ dinv, __half* __restrict__ hp) {
    __shared__ float Wl[H_DIM * 64];
    __shared__ float scl[64], shl[64];
    for (int i = threadIdx.x * 4; i < H_DIM * 64; i += 256 * 4)
        *(float4*)&Wl[i] = *(const float4*)&W[i];
    if (threadIdx.x < 64) { scl[threadIdx.x] = scale[threadIdx.x]; shl[threadIdx.x] = shift[threadIdx.x]; }
    __syncthreads();
    int c4 = (threadIdx.x & 15) * 4;
    int n0 = blockIdx.x * 64 + (threadIdx.x >> 4) * 4;
    if (n0 >= N_NODES) return;
    float4 acc0 = {0,0,0,0}, acc1 = {0,0,0,0}, acc2 = {0,0,0,0}, acc3 = {0,0,0,0};
    #pragma unroll 4
    for (int k = 0; k < H_DIM; k += 4) {
        float4 w0 = *(float4*)&Wl[(k + 0) * 64 + c4];
        float4 w1 = *(float4*)&Wl[(k + 1) * 64 + c4];
        float4 w2 = *(float4*)&Wl[(k + 2) * 64 + c4];
        float4 w3 = *(float4*)&Wl[(k + 3) * 64 + c4];
        float4 s4 = *(float4*)&scl[k];
        float4 f4 = *(float4*)&shl[k];
        #define DO_NODE(ACC, I)                                                        \
        {   h4 r = *(const h4*)&Z[(size_t)(n0 + I) * 64 + k];                          \
            float2 p = __half22float2(r.a), q = __half22float2(r.b);                   \
            float z0 = fmaf(p.x, s4.x, f4.x), z1 = fmaf(p.y, s4.y, f4.y);              \
            float z2 = fmaf(q.x, s4.z, f4.z), z3 = fmaf(q.y, s4.w, f4.w);              \
            fma4(ACC, z0, w0); fma4(ACC, z1, w1); fma4(ACC, z2, w2); fma4(ACC, z3, w3); }
        DO_NODE(acc0, 0) DO_NODE(acc1, 1) DO_NODE(acc2, 2) DO_NODE(acc3, 3)
        #undef DO_NODE
    }
    float d0 = dinv[n0], d1 = dinv[n0 + 1], d2 = dinv[n0 + 2], d3 = dinv[n0 + 3];
    acc0.x *= d0; acc0.y *= d0; acc0.z *= d0; acc0.w *= d0;
    acc1.x *= d1; acc1.y *= d1; acc1.z *= d1; acc1.w *= d1;
    acc2.x *= d2; acc2.y *= d2; acc2.z *= d2; acc2.w *= d2;
    acc3.x *= d3; acc3.y *= d3; acc3.z *= d3; acc3.w *= d3;
    *(h4*)&hp[(size_t)(n0 + 0) * 64 + c4] = pack_h4(acc0);
    *(h4*)&hp[(size_t)(n0 + 1) * 64 + c4] = pack_h4(acc1);
    *(h4*)&hp[(size_t)(n0 + 2) * 64 + c4] = pack_h4(acc2);
    *(h4*)&hp[(size_t)(n0 + 3) * 64 + c4] = pack_h4(acc3);
}

// ---------- aggregate + relu (pre-scaled hp, pure adds, x2 edge ILP) ----------
// z = relu((sum_e hp[s] + hp[i]) * dinv[i] + bias)   where hp = h*dinv

__global__ __launch_bounds__(256) void aggregate_k(
        const __half* __restrict__ hp, const float* __restrict__ dinv,
        const int* __restrict__ offsets, const int* __restrict__ counts,
        const unsigned short* __restrict__ ssrc, const float* __restrict__ bias,
        __half* __restrict__ zb) {
    int wid = (blockIdx.x * blockDim.x + threadIdx.x) >> 6;   // node (grid exact)
    int lane = threadIdx.x & 63;
    int g = lane >> 3;            // edge sub-slot 0..7
    int c8 = (lane & 7) * 8;      // channel base
    float a0=0,a1=0,a2=0,a3=0,a4=0,a5=0,a6=0,a7=0;
    int s0 = offsets[wid];
    int ce = counts[wid];
    int e = g;
    for (; e + 8 < ce; e += 16) {
        int s1 = ssrc[s0 + e];
        int s2 = ssrc[s0 + e + 8];
        h8 v1 = *(const h8*)(hp + (size_t)s1 * 64 + c8);
        h8 v2 = *(const h8*)(hp + (size_t)s2 * 64 + c8);
        float2 f0 = __half22float2(v1.a), f1 = __half22float2(v1.b);
        float2 f2 = __half22float2(v1.c), f3 = __half22float2(v1.d);
        float2 g0 = __half22float2(v2.a), g1 = __half22float2(v2.b);
        float2 g2 = __half22float2(v2.c), g3 = __half22float2(v2.d);
        a0 += f0.x + g0.x; a1 += f0.y + g0.y; a2 += f1.x + g1.x; a3 += f1.y + g1.y;
        a4 += f2.x + g2.x; a5 += f2.y + g2.y; a6 += f3.x + g3.x; a7 += f3.y + g3.y;
    }
    if (e < ce) {
        int s = ssrc[s0 + e];
        h8 v = *(const h8*)(hp + (size_t)s * 64 + c8);
        float2 f0 = __half22float2(v.a), f1 = __half22float2(v.b);
        float2 f2 = __half22float2(v.c), f3 = __half22float2(v.d);
        a0 += f0.x; a1 += f0.y; a2 += f1.x; a3 += f1.y;
        a4 += f2.x; a5 += f2.y; a6 += f3.x; a7 += f3.y;
    }
    #define RED(A) A += __shfl_xor(A, 8); A += __shfl_xor(A, 16); A += __shfl_xor(A, 32);
    RED(a0) RED(a1) RED(a2) RED(a3) RED(a4) RED(a5) RED(a6) RED(a7)
    #undef RED
    if (g == 0) {
        h8 sv = *(const h8*)(hp + (size_t)wid * 64 + c8);
        float2 f0 = __half22float2(sv.a), f1 = __half22float2(sv.b);
        float2 f2 = __half22float2(sv.c), f3 = __half22float2(sv.d);
        float di = dinv[wid];
        float4 b0 = *(const float4*)&bias[c8];
        float4 b1 = *(const float4*)&bias[c8 + 4];
        float o0 = fmaxf(fmaf(a0 + f0.x, di, b0.x), 0.f);
        float o1 = fmaxf(fmaf(a1 + f0.y, di, b0.y), 0.f);
        float o2 = fmaxf(fmaf(a2 + f1.x, di, b0.z), 0.f);
        float o3 = fmaxf(fmaf(a3 + f1.y, di, b0.w), 0.f);
        float o4 = fmaxf(fmaf(a4 + f2.x, di, b1.x), 0.f);
        float o5 = fmaxf(fmaf(a5 + f2.y, di, b1.y), 0.f);
        float o6 = fmaxf(fmaf(a6 + f3.x, di, b1.z), 0.f);
        float o7 = fmaxf(fmaf(a7 + f3.y, di, b1.w), 0.f);
        h8 ov;
        ov.a = __float22half2_rn(make_float2(o0, o1));
        ov.b = __float22half2_rn(make_float2(o2, o3));
        ov.c = __float22half2_rn(make_float2(o4, o5));
        ov.d = __float22half2_rn(make_float2(o6, o7));
        *(h8*)(zb + (size_t)wid * 64 + c8) = ov;
    }
}

// ---------- BN stats: streaming over zb, 8 replica slots ----------

__global__ __launch_bounds__(256) void bn_stats_k(const __half* __restrict__ zb,
                                                  float* __restrict__ slots) {
    int slot = threadIdx.x & 7;
    int rp = threadIdx.x >> 3;
    float s[8], q[8];
    #pragma unroll
    for (int j = 0; j < 8; j++) { s[j] = 0.f; q[j] = 0.f; }
    for (int n = blockIdx.x * 32 + rp; n < N_NODES; n += 256 * 32) {
        h8 v = *(const h8*)(zb + (size_t)n * 64 + slot * 8);
        float2 f0 = __half22float2(v.a), f1 = __half22float2(v.b);
        float2 f2 = __half22float2(v.c), f3 = __half22float2(v.d);
        float x0 = f0.x, x1 = f0.y, x2 = f1.x, x3 = f1.y;
        float x4 = f2.x, x5 = f2.y, x6 = f3.x, x7 = f3.y;
        s[0] += x0; q[0] += x0 * x0; s[1] += x1; q[1] += x1 * x1;
        s[2] += x2; q[2] += x2 * x2; s[3] += x3; q[3] += x3 * x3;
        s[4] += x4; q[4] += x4 * x4; s[5] += x5; q[5] += x5 * x5;
        s[6] += x6; q[6] += x6 * x6; s[7] += x7; q[7] += x7 * x7;
    }
    #pragma unroll
    for (int j = 0; j < 8; j++) {
        float a = s[j];
        a += __shfl_xor(a, 8); a += __shfl_xor(a, 16); a += __shfl_xor(a, 32);
        s[j] = a;
        float b = q[j];
        b += __shfl_xor(b, 8); b += __shfl_xor(b, 16); b += __shfl_xor(b, 32);
        q[j] = b;
    }
    __shared__ float rs[4][64], rq[4][64];
    int w = threadIdx.x >> 6;
    if ((threadIdx.x & 63) < 8) {
        #pragma unroll
        for (int j = 0; j < 8; j++) {
            rs[w][slot * 8 + j] = s[j];
            rq[w][slot * 8 + j] = q[j];
        }
    }
    __syncthreads();
    int t = threadIdx.x;
    int rep = (blockIdx.x & 7) * 128;
    if (t < 64)
        atomicAdd(&slots[rep + t], rs[0][t] + rs[1][t] + rs[2][t] + rs[3][t]);
    else if (t < 128) {
        int c = t - 64;
        atomicAdd(&slots[rep + t], rq[0][c] + rq[1][c] + rq[2][c] + rq[3][c]);
    }
}

__global__ void bn_finalize_k(float* __restrict__ slots,
                              const float* __restrict__ gamma, const float* __restrict__ beta,
                              float* __restrict__ scale, float* __restrict__ shift) {
    __shared__ float red[128];
    int c = threadIdx.x;
    float v = 0.f;
    #pragma unroll
    for (int r = 0; r < 8; r++) v += slots[r * 128 + c];
    red[c] = v;
    __syncthreads();
    if (c < 64) {
        float mu = red[c] * (1.0f / N_NODES);
        float var = red[c + 64] * (1.0f / N_NODES) - mu * mu;
        float k = gamma[c] * rsqrtf(var + EPS_BN);
        scale[c] = k;
        shift[c] = beta[c] - mu * k;
    }
    #pragma unroll
    for (int i = 0; i < 8; i++) slots[i * 128 + c] = 0.f;
}

// ---------- fused epilogue: blocks 0..255 pool+norm gc, rest l2norm zc ----------

__global__ __launch_bounds__(256) void epilogue_k(
        const __half* __restrict__ zb0, const __half* __restrict__ zb1,
        const __half* __restrict__ zb2,
        const float* __restrict__ scaleAll, const float* __restrict__ shiftAll,
        const int* __restrict__ batch, float* __restrict__ gc,
        float* __restrict__ zc) {
    if (blockIdx.x < N_GRAPHS) {
        int g = blockIdx.x;
        int lo = 0, hi = N_NODES;
        while (lo < hi) { int mid = (lo + hi) >> 1; if (batch[mid] < g) lo = mid + 1; else hi = mid; }
        int start = lo;
        hi = N_NODES;
        while (lo < hi) { int mid = (lo + hi) >> 1; if (batch[mid] < g + 1) lo = mid + 1; else hi = mid; }
        int end = lo;

        int slot = threadIdx.x & 7;
        int r = threadIdx.x >> 3;
        const __half* zbs[3] = {zb0, zb1, zb2};
        float acc[3][8];
        #pragma unroll
        for (int l = 0; l < 3; l++)
            #pragma unroll
            for (int j = 0; j < 8; j++) acc[l][j] = 0.f;
        #pragma unroll
        for (int l = 0; l < 3; l++) {
            const __half* z = zbs[l];
            for (int n = start + r; n < end; n += 32) {
                h8 v = *(const h8*)(z + (size_t)n * 64 + slot * 8);
                float2 f0 = __half22float2(v.a), f1 = __half22float2(v.b);
                float2 f2 = __half22float2(v.c), f3 = __half22float2(v.d);
                acc[l][0] += f0.x; acc[l][1] += f0.y; acc[l][2] += f1.x; acc[l][3] += f1.y;
                acc[l][4] += f2.x; acc[l][5] += f2.y; acc[l][6] += f3.x; acc[l][7] += f3.y;
            }
        }
        #pragma unroll
        for (int l = 0; l < 3; l++)
            #pragma unroll
            for (int j = 0; j < 8; j++) {
                float a = acc[l][j];
                a += __shfl_xor(a, 8);
                a += __shfl_xor(a, 16);
                a += __shfl_xor(a, 32);
                acc[l][j] = a;
            }
        __shared__ float red[4][3][64];
        int w = threadIdx.x >> 6;
        if ((threadIdx.x & 63) < 8) {
            #pragma unroll
            for (int l = 0; l < 3; l++)
                #pragma unroll
                for (int j = 0; j < 8; j++)
                    red[w][l][slot * 8 + j] = acc[l][j];
        }
        __syncthreads();
        __shared__ float part[4];
        int t = threadIdx.x;
        float m = 0.f;
        if (t < 192) {
            int l = t >> 6, ch = t & 63;
            float s = red[0][l][ch] + red[1][l][ch] + red[2][l][ch] + red[3][l][ch];
            m = (end > start) ? fmaf(scaleAll[t], s / (float)(end - start), shiftAll[t]) : 0.f;
        }
        float q = m * m;
        #pragma unroll
        for (int off = 32; off; off >>= 1) q += __shfl_xor(q, off);
        if ((t & 63) == 0) part[t >> 6] = q;
        __syncthreads();
        float inv = 1.0f / fmaxf(sqrtf(part[0] + part[1] + part[2] + part[3]), 1e-12f);
        if (t < 192) gc[(size_t)g * 192 + t] = m * inv;
        return;
    }
    // l2norm branch: 12500 blocks x 4 waves, wid exact
    int wid = ((blockIdx.x - N_GRAPHS) * 256 + threadIdx.x) >> 6;
    int lane = threadIdx.x & 63;
    float a = fmaf(__half2float(zb0[(size_t)wid * 64 + lane]), scaleAll[lane],       shiftAll[lane]);
    float b = fmaf(__half2float(zb1[(size_t)wid * 64 + lane]), scaleAll[64 + lane],  shiftAll[64 + lane]);
    float c = fmaf(__half2float(zb2[(size_t)wid * 64 + lane]), scaleAll[128 + lane], shiftAll[128 + lane]);
    float s = a * a + b * b + c * c;
    #pragma unroll
    for (int off = 32; off; off >>= 1) s += __shfl_xor(s, off);
    float inv = 1.0f / fmaxf(sqrtf(s), 1e-12f);
    float* row = zc + (size_t)wid * 192;
    row[lane] = a * inv; row[lane + 64] = b * inv; row[lane + 128] = c * inv;
}

// ---------- launch ----------

extern "C" void kernel_launch(void* const* d_in, const int* in_sizes, int n_in,
                              void* d_out, int out_size, void* d_ws, size_t ws_size,
                              hipStream_t stream) {
    const float* x     = (const float*)d_in[0];
    const int*   ei    = (const int*)d_in[1];
    const int*   batch = (const int*)d_in[2];
    const float* W[3]     = {(const float*)d_in[3],  (const float*)d_in[7],  (const float*)d_in[11]};
    const float* bias[3]  = {(const float*)d_in[4],  (const float*)d_in[8],  (const float*)d_in[12]};
    const float* gamma[3] = {(const float*)d_in[5],  (const float*)d_in[9],  (const float*)d_in[13]};
    const float* beta[3]  = {(const float*)d_in[6],  (const float*)d_in[10], (const float*)d_in[14]};
    const int* src = ei;
    const int* dst = ei + N_EDGES;

    float* out = (float*)d_out;
    float* zc = out;                                // [N, 192]
    float* gc = out + (size_t)N_NODES * 192;        // [G, 192]

    char* w = (char*)d_ws;
    auto alloc = [&](size_t bytes) -> void* {
        void* p = (void*)w;
        w += (bytes + 255) / 256 * 256;
        return p;
    };
    int*            counts    = (int*)alloc(N_NODES * 4);
    int*            offsets   = (int*)alloc(N_NODES * 4);
    float*          dinv      = (float*)alloc(N_NODES * 4);
    unsigned short* ssrc      = (unsigned short*)alloc(N_EDGES * 2);
    __half*         hp        = (__half*)alloc((size_t)N_NODES * 64 * 2);
    __half*         zb[3];
    zb[0] = (__half*)alloc((size_t)N_NODES * 64 * 2);
    zb[1] = (__half*)alloc((size_t)N_NODES * 64 * 2);
    zb[2] = (__half*)alloc((size_t)N_NODES * 64 * 2);
    float*          slots     = (float*)alloc(8 * 128 * 4);
    float*          scaleAll  = (float*)alloc(192 * 4);
    float*          shiftAll  = (float*)alloc(192 * 4);
    // Overlays (strictly sequential lifetimes, fully rewritten each call):
    //   ebuf (3.2MB) on zb[1]; cntM/baseM/beb (257KB) on zb[2].
    unsigned int* ebuf  = (unsigned int*)zb[1];
    int*          cntM  = (int*)zb[2];
    int*          baseM = (int*)((char*)zb[2] + NC * NB * 4);
    int*          beb   = (int*)((char*)zb[2] + 2 * NC * NB * 4);

    hipMemsetAsync(slots, 0, 8 * 128 * 4, stream);
    cnt_gemm0_k<<<NC + GEMM0_BLOCKS, 256, 0, stream>>>(x, W[0], hp, dst, cntM);
    scanM_k<<<1, NB, 0, stream>>>(cntM, baseM, beb);
    scatter_k<<<NC, 256, 0, stream>>>(src, dst, baseM, beb, ebuf);
    fill_k<<<NB, 256, 0, stream>>>(ebuf, beb, counts, offsets, dinv, ssrc);
    scale_hp_k<<<(N_NODES * 8 + 255) / 256, 256, 0, stream>>>(hp, dinv);

    const int aggBlocks = N_NODES / 4;   // 12500, exact

    for (int l = 0; l < 3; l++) {
        if (l > 0)
            gemm_h_k<<<GEMM0_BLOCKS, 256, 0, stream>>>(zb[l - 1], W[l],
                                                       scaleAll + (l - 1) * 64, shiftAll + (l - 1) * 64,
                                                       dinv, hp);
        aggregate_k<<<aggBlocks, 256, 0, stream>>>(hp, dinv, offsets, counts, ssrc,
                                                   bias[l], zb[l]);
        bn_stats_k<<<256, 256, 0, stream>>>(zb[l], slots);
        bn_finalize_k<<<1, 128, 0, stream>>>(slots, gamma[l], beta[l],
                                             scaleAll + l * 64, shiftAll + l * 64);
    }

    epilogue_k<<<N_GRAPHS + N_NODES / 4, 256, 0, stream>>>(zb[0], zb[1], zb[2],
                                                           scaleAll, shiftAll, batch, gc, zc);
}